// Round 4
// baseline (617.951 us; speedup 1.0000x reference)
//
#include <hip/hip_runtime.h>
#include <hip/hip_bf16.h>

// Problem constants
#define Bsz 4
#define Tsz 2048
#define Dsz 1024
#define Ssz 16
#define Esz 2048
#define Mrows (Bsz*Tsz)        // 8192

typedef __attribute__((ext_vector_type(8))) short short8;
typedef __attribute__((ext_vector_type(4))) float floatx4;

__device__ __forceinline__ void async_ld16(const void* g, void* l) {
    __builtin_amdgcn_global_load_lds(
        (const __attribute__((address_space(1))) void*)g,
        (__attribute__((address_space(3))) void*)l,
        16, 0, 0);
}

__device__ __forceinline__ float sigmoidf_(float v) { return 1.f / (1.f + expf(-v)); }
__device__ __forceinline__ float bf2f(unsigned short u) {
    union { unsigned u32; float f; } c; c.u32 = (unsigned)u << 16; return c.f;
}

// ---------------------------------------------------------------------------
// merged fp32 -> bf16 conversion for x, in_w, dt_w, out_w (float4 granules)
// ---------------------------------------------------------------------------
#define CVT_S0 2097152   // x:     8388608 f32 / 4
#define CVT_S1 3145728   // in_w: +4194304 / 4
#define CVT_S2 4194304   // dt_w: +4194304 / 4
#define CVT_S3 4718592   // out_w:+2097152 / 4
__global__ void cvt_all(const float4* __restrict__ x,  const float4* __restrict__ iw,
                        const float4* __restrict__ dw, const float4* __restrict__ ow,
                        ushort4* __restrict__ xb,  ushort4* __restrict__ iwb,
                        ushort4* __restrict__ dwb, ushort4* __restrict__ owb) {
    int i = blockIdx.x * blockDim.x + threadIdx.x;
    const int stride = gridDim.x * blockDim.x;
    for (; i < CVT_S3; i += stride) {
        float4 v; ushort4* dst; int j;
        if (i < CVT_S0)      { v = x [j = i];           dst = xb  + j; }
        else if (i < CVT_S1) { v = iw[j = i - CVT_S0];  dst = iwb + j; }
        else if (i < CVT_S2) { v = dw[j = i - CVT_S1];  dst = dwb + j; }
        else                 { v = ow[j = i - CVT_S2];  dst = owb + j; }
        __hip_bfloat16 a = __float2bfloat16(v.x), b = __float2bfloat16(v.y);
        __hip_bfloat16 c = __float2bfloat16(v.z), d = __float2bfloat16(v.w);
        ushort4 o;
        o.x = *(unsigned short*)&a; o.y = *(unsigned short*)&b;
        o.z = *(unsigned short*)&c; o.w = *(unsigned short*)&d;
        *dst = o;
    }
}

// ---------------------------------------------------------------------------
// bf16 GEMM: C[M,N] = A[M,K] @ Bw[N,K]^T (+bias).
// Block tile = (32*TM) x (32*TN), 4 waves in 2x2, each wave (16*TM)x(16*TN)
// via TMxTN mfma_f32_16x16x32_bf16 (big register tile: 0.25 LDS reads/MFMA
// at TM=TN=8 vs 0.5 for 64x64 waves -- we are LDS-pipe-bound).
// LDS layout XOR-swizzled: slot s of row r holds global chunk s^((r>>1)&3),
// making frag ds_read_b128 2-way bank-conflicted (free) instead of 8-way.
// Software-pipelined: double LDS buffer, prefetch distance 2,
// s_waitcnt vmcnt(NW) + raw barriers (never vmcnt(0) in-loop).
// MODE: 0 bf16 store, 1 softplus rowsum, 2 fp32 + resid.
// ---------------------------------------------------------------------------
template<int MODE, int TM, int TN>
__launch_bounds__(256, 1)
__global__ void gemm_bt(const __hip_bfloat16* __restrict__ A,
                        const __hip_bfloat16* __restrict__ Bw,
                        const float* __restrict__ bias,
                        int M, int N, int K,
                        __hip_bfloat16* __restrict__ outb,
                        float* __restrict__ rowsum,
                        const float* __restrict__ resid,
                        float* __restrict__ outf) {
    constexpr int BM = 32 * TM, BN = 32 * TN;
    constexpr int A_ISS = BM / 64, B_ISS = BN / 64;       // issues/wave/tile
    constexpr int NW = A_ISS + B_ISS;                     // vmcnt per tile
    constexpr int ABUF = BM * 32, BBUF = BN * 32;         // elements/buffer

    __shared__ __align__(16) __hip_bfloat16 sA[2 * ABUF];
    __shared__ __align__(16) __hip_bfloat16 sB[2 * BBUF];

    const int tid  = threadIdx.x;
    const int wave = tid >> 6, lane = tid & 63;
    const int wm = wave >> 1, wn = wave & 1;
    const int q = lane >> 4, lr = lane & 15;
    const int m0 = blockIdx.y * BM, n0 = blockIdx.x * BN;

    floatx4 acc[TM][TN];
#pragma unroll
    for (int i = 0; i < TM; ++i)
#pragma unroll
        for (int j = 0; j < TN; ++j) acc[i][j] = (floatx4){0.f, 0.f, 0.f, 0.f};

    // staging pointers: chunk c = issue*256 + tid -> (row=c>>2, slot=c&3);
    // fetch global chunk slot^((row>>1)&3) so swizzled LDS slot holds it.
    const __hip_bfloat16* pa[A_ISS];
    const __hip_bfloat16* pb[B_ISS];
#pragma unroll
    for (int i = 0; i < A_ISS; ++i) {
        const int c = i * 256 + tid, row = c >> 2, slot = c & 3;
        const int gcol = ((slot ^ ((row >> 1) & 3)) << 3);
        pa[i] = A + (size_t)(m0 + row) * K + gcol;
    }
#pragma unroll
    for (int i = 0; i < B_ISS; ++i) {
        const int c = i * 256 + tid, row = c >> 2, slot = c & 3;
        const int gcol = ((slot ^ ((row >> 1) & 3)) << 3);
        pb[i] = Bw + (size_t)(n0 + row) * K + gcol;
    }

    // fragment LDS offsets (swizzled), precomputed once
    int aoff[TM], boff[TN];
#pragma unroll
    for (int i = 0; i < TM; ++i) {
        const int r = wm * TM * 16 + i * 16 + lr;
        aoff[i] = r * 32 + ((q ^ ((r >> 1) & 3)) << 3);
    }
#pragma unroll
    for (int j = 0; j < TN; ++j) {
        const int r = wn * TN * 16 + j * 16 + lr;
        boff[j] = r * 32 + ((q ^ ((r >> 1) & 3)) << 3);
    }

    auto issue = [&](int koff, int cur) {
#pragma unroll
        for (int i = 0; i < A_ISS; ++i)
            async_ld16(pa[i] + koff, &sA[cur * ABUF + (i * 256 + wave * 64) * 8]);
#pragma unroll
        for (int i = 0; i < B_ISS; ++i)
            async_ld16(pb[i] + koff, &sB[cur * BBUF + (i * 256 + wave * 64) * 8]);
    };

    const int nkt = K >> 5;
    issue(0, 0);
    issue(32, 1);
    int koff = 64;

    for (int kt = 0; kt < nkt; ++kt) {
        const int cur = kt & 1;
        asm volatile("" ::: "memory");
        __builtin_amdgcn_s_waitcnt(0xF70 | NW);   // vmcnt(NW): tile kt ready
        __builtin_amdgcn_s_barrier();
        asm volatile("" ::: "memory");

        const __hip_bfloat16* sa = &sA[cur * ABUF];
        const __hip_bfloat16* sb = &sB[cur * BBUF];
        short8 af[TM], bfv[TN];
#pragma unroll
        for (int i = 0; i < TM; ++i) af[i]  = *(const short8*)&sa[aoff[i]];
#pragma unroll
        for (int j = 0; j < TN; ++j) bfv[j] = *(const short8*)&sb[boff[j]];

        asm volatile("" ::: "memory");
        __builtin_amdgcn_s_waitcnt(0xC07F);       // lgkmcnt(0): frags landed
        __builtin_amdgcn_s_barrier();
        asm volatile("" ::: "memory");

        issue(koff, cur);                          // tile kt+2 -> buf[cur]
        if (kt < nkt - 3) koff += 32;              // clamp keeps vmcnt uniform

#pragma unroll
        for (int i = 0; i < TM; ++i)
#pragma unroll
            for (int j = 0; j < TN; ++j)
                acc[i][j] = __builtin_amdgcn_mfma_f32_16x16x32_bf16(af[i], bfv[j], acc[i][j], 0, 0, 0);
    }
    asm volatile("" ::: "memory");
    __builtin_amdgcn_s_waitcnt(0x70);             // vmcnt(0): drain tail DMA

    // epilogue: C/D layout col = lane&15, row = (lane>>4)*4 + reg
    if (MODE == 0) {
#pragma unroll
        for (int i = 0; i < TM; ++i) {
            const int row = m0 + wm * TM * 16 + i * 16 + q * 4;
#pragma unroll
            for (int j = 0; j < TN; ++j) {
                const int col = n0 + wn * TN * 16 + j * 16 + lr;
                const float bc = bias[col];
#pragma unroll
                for (int r = 0; r < 4; ++r)
                    outb[(size_t)(row + r) * N + col] = __float2bfloat16(acc[i][j][r] + bc);
            }
        }
    } else if (MODE == 1) {
#pragma unroll
        for (int i = 0; i < TM; ++i) {
            float rs[4] = {0.f, 0.f, 0.f, 0.f};
#pragma unroll
            for (int j = 0; j < TN; ++j) {
                const int col = n0 + wn * TN * 16 + j * 16 + lr;
                const float bc = bias[col];
#pragma unroll
                for (int r = 0; r < 4; ++r) {
                    float v = acc[i][j][r] + bc;
                    float sp = (v > 20.f) ? v : log1pf(expf(v));
                    rs[r] += sp;
                }
            }
#pragma unroll
            for (int r = 0; r < 4; ++r) {
                float v = rs[r];
                v += __shfl_xor(v, 1); v += __shfl_xor(v, 2);
                v += __shfl_xor(v, 4); v += __shfl_xor(v, 8);
                if (lr == 0)
                    atomicAdd(&rowsum[m0 + wm * TM * 16 + i * 16 + q * 4 + r], v);
            }
        }
    } else {
#pragma unroll
        for (int i = 0; i < TM; ++i) {
            const int row = m0 + wm * TM * 16 + i * 16 + q * 4;
#pragma unroll
            for (int j = 0; j < TN; ++j) {
                const int col = n0 + wn * TN * 16 + j * 16 + lr;
                const float bc = bias[col];
#pragma unroll
                for (int r = 0; r < 4; ++r) {
                    const size_t idx = (size_t)(row + r) * N + col;
                    outf[idx] = acc[i][j][r] + bc + resid[idx];
                }
            }
        }
    }
}

// ---------------------------------------------------------------------------
// depthwise conv (k=3, pad 1, along T) + bias + SiLU, 8 channels per thread.
// ---------------------------------------------------------------------------
__global__ void conv_silu_k(const __hip_bfloat16* __restrict__ xp,
                            const float* __restrict__ cw,
                            const float* __restrict__ cb,
                            __hip_bfloat16* __restrict__ xc) {
    const int idx8 = blockIdx.x * blockDim.x + threadIdx.x;
    const int e = (idx8 & (Esz / 8 - 1)) * 8;
    const int r = idx8 >> 8;
    const int t = r & (Tsz - 1);
    const unsigned short* row0 = (const unsigned short*)(xp + (size_t)r * (2 * Esz) + e);
    short8 vm1 = (t > 0)       ? *(const short8*)(row0 - 2 * Esz) : (short8){0,0,0,0,0,0,0,0};
    short8 v00 = *(const short8*)row0;
    short8 vp1 = (t < Tsz - 1) ? *(const short8*)(row0 + 2 * Esz) : (short8){0,0,0,0,0,0,0,0};
    short8 o;
#pragma unroll
    for (int k = 0; k < 8; ++k) {
        const int ek = e + k;
        float v = bf2f((unsigned short)vm1[k]) * cw[ek * 3 + 0]
                + bf2f((unsigned short)v00[k]) * cw[ek * 3 + 1]
                + bf2f((unsigned short)vp1[k]) * cw[ek * 3 + 2] + cb[ek];
        __hip_bfloat16 h = __float2bfloat16(v * sigmoidf_(v));
        o[k] = *(short*)&h;
    }
    *(short8*)(xc + (size_t)idx8 * 8) = o;
}

// ---------------------------------------------------------------------------
// pack B_w/C_w/D_w (each [16,2048] fp32) into Wb [48,2048] bf16
// ---------------------------------------------------------------------------
__global__ void pack_bcd(const float* __restrict__ Bw, const float* __restrict__ Cw,
                         const float* __restrict__ Dw, __hip_bfloat16* __restrict__ Wb) {
    const int idx = blockIdx.x * blockDim.x + threadIdx.x;
    if (idx >= 48 * Esz) return;
    const int row = idx >> 11, col = idx & (Esz - 1);
    float v;
    if (row < 16)      v = Bw[row * Esz + col];
    else if (row < 32) v = Cw[(row - 16) * Esz + col];
    else               v = Dw[(row - 32) * Esz + col];
    Wb[idx] = __float2bfloat16(v);
}

// ---------------------------------------------------------------------------
// B/C/D projections via MFMA skinny GEMM: xc[M,E] @ Wb[48,E]^T.
// ---------------------------------------------------------------------------
__launch_bounds__(256)
__global__ void bcd_mfma(const __hip_bfloat16* __restrict__ xc,
                         const __hip_bfloat16* __restrict__ Wb,
                         const float* __restrict__ Bb, const float* __restrict__ Cb,
                         const float* __restrict__ Db,
                         float* __restrict__ u, float* __restrict__ Ct) {
    __shared__ __align__(16) __hip_bfloat16 sA[64 * 32];
    __shared__ __align__(16) __hip_bfloat16 sW[48 * 32];
    const int tid = threadIdx.x;
    const int wave = tid >> 6, lane = tid & 63;
    const int q = lane >> 4, lr = lane & 15;
    const int m0 = blockIdx.x * 64;

    floatx4 acc[3];
#pragma unroll
    for (int j = 0; j < 3; ++j) acc[j] = (floatx4){0.f, 0.f, 0.f, 0.f};

    const int ra = wave * 16 + (lane >> 2);
    const int ca = (lane & 3) * 8;

    for (int kt = 0; kt < (Esz >> 5); ++kt) {
        const int k0 = kt << 5;
        __syncthreads();
        async_ld16(&xc[(size_t)(m0 + ra) * Esz + k0 + ca], &sA[wave * 512]);
        if (wave < 3)
            async_ld16(&Wb[(size_t)ra * Esz + k0 + ca], &sW[wave * 512]);
        __syncthreads();

        short8 af = *(const short8*)&sA[(wave * 16 + lr) * 32 + q * 8];
#pragma unroll
        for (int j = 0; j < 3; ++j) {
            short8 wf = *(const short8*)&sW[(j * 16 + lr) * 32 + q * 8];
            acc[j] = __builtin_amdgcn_mfma_f32_16x16x32_bf16(af, wf, acc[j], 0, 0, 0);
        }
    }

    const int row = m0 + wave * 16 + q * 4;
    const float bb = Bb[lr], cbv = Cb[lr], db = Db[lr];
#pragma unroll
    for (int r = 0; r < 4; ++r) {
        const float bt = acc[0][r] + bb;
        const float ct = acc[1][r] + cbv;
        const float dt = acc[2][r] + db;
        u [(size_t)(row + r) * Ssz + lr] = bt * dt;
        Ct[(size_t)(row + r) * Ssz + lr] = ct;
    }
}

// ---------------------------------------------------------------------------
// Sequential SSM scan (decay computed inline from rowsum).  One block/batch.
// ---------------------------------------------------------------------------
__global__ void scan_k(const float* __restrict__ rowsum, const float* __restrict__ u,
                       const float* __restrict__ Ct, float* __restrict__ ys) {
    const int b = blockIdx.x;
    const int tid = threadIdx.x;
    const int lane = tid & 63, wave = tid >> 6;
    __shared__ __align__(16) float su[256 * Ssz];
    __shared__ __align__(16) float sc[256 * Ssz];
    __shared__ float sp[256 * 17];
    __shared__ float sd[256];
    float st = 0.f;
    for (int t0 = 0; t0 < Tsz; t0 += 256) {
        __syncthreads();
        const float4* ub = (const float4*)(u  + ((size_t)b * Tsz + t0) * Ssz);
        const float4* cb = (const float4*)(Ct + ((size_t)b * Tsz + t0) * Ssz);
#pragma unroll
        for (int i = 0; i < 4; ++i) {
            ((float4*)su)[tid + i * 256] = ub[tid + i * 256];
            ((float4*)sc)[tid + i * 256] = cb[tid + i * 256];
        }
        {
            const float m = rowsum[b * Tsz + t0 + tid] * (1.f / (float)Esz);
            sd[tid] = expf(fminf(fmaxf(-m, -10.f), 10.f));
        }
        __syncthreads();
        if (wave == 0 && lane < 16) {
#pragma unroll 8
            for (int i = 0; i < 256; ++i) {
                st = st * sd[i] + su[i * Ssz + lane];
                sp[i * 17 + lane] = sc[i * Ssz + lane] * st;
            }
        }
        __syncthreads();
        float s = 0.f;
#pragma unroll
        for (int j = 0; j < 16; ++j) s += sp[tid * 17 + j];
        ys[b * Tsz + t0 + tid] = s;
    }
}

// ---------------------------------------------------------------------------
// y[r,e] = ys[r] * silu(x_gate[r,e]), 8 per thread; gate = xp cols [E,2E).
// ---------------------------------------------------------------------------
__global__ void ygate_k(const float* __restrict__ ys, const __hip_bfloat16* __restrict__ xp,
                        __hip_bfloat16* __restrict__ y) {
    const int idx8 = blockIdx.x * blockDim.x + threadIdx.x;
    const int e = (idx8 & (Esz / 8 - 1)) * 8;
    const int r = idx8 >> 8;
    const float yr = ys[r];
    short8 g = *(const short8*)(xp + (size_t)r * (2 * Esz) + Esz + e);
    short8 o;
#pragma unroll
    for (int k = 0; k < 8; ++k) {
        const float gv = bf2f((unsigned short)g[k]);
        __hip_bfloat16 h = __float2bfloat16(yr * gv * sigmoidf_(gv));
        o[k] = *(short*)&h;
    }
    *(short8*)(y + (size_t)idx8 * 8) = o;
}

// ---------------------------------------------------------------------------
extern "C" void kernel_launch(void* const* d_in, const int* in_sizes, int n_in,
                              void* d_out, int out_size, void* d_ws, size_t ws_size,
                              hipStream_t stream) {
    const float* x      = (const float*)d_in[0];
    const float* in_w   = (const float*)d_in[1];
    const float* in_b   = (const float*)d_in[2];
    const float* conv_w = (const float*)d_in[3];
    const float* conv_b = (const float*)d_in[4];
    const float* dt_w   = (const float*)d_in[5];
    const float* dt_b   = (const float*)d_in[6];
    const float* B_w    = (const float*)d_in[7];
    const float* B_b    = (const float*)d_in[8];
    const float* C_w    = (const float*)d_in[9];
    const float* C_b    = (const float*)d_in[10];
    const float* D_w    = (const float*)d_in[11];
    const float* D_b    = (const float*)d_in[12];
    const float* out_w  = (const float*)d_in[13];
    const float* out_b  = (const float*)d_in[14];
    float* out = (float*)d_out;

    char* ws = (char*)d_ws;
    auto alloc = [&](size_t bytes) {
        char* p = ws;
        ws += (bytes + 255) & ~(size_t)255;
        return p;
    };
    __hip_bfloat16* x_bf    = (__hip_bfloat16*)alloc((size_t)Mrows * Dsz * 2);
    __hip_bfloat16* inw_bf  = (__hip_bfloat16*)alloc((size_t)2 * Esz * Dsz * 2);
    __hip_bfloat16* dtw_bf  = (__hip_bfloat16*)alloc((size_t)Esz * Esz * 2);
    __hip_bfloat16* outw_bf = (__hip_bfloat16*)alloc((size_t)Dsz * Esz * 2);
    __hip_bfloat16* xp_bf   = (__hip_bfloat16*)alloc((size_t)Mrows * 2 * Esz * 2);
    __hip_bfloat16* xc_bf   = (__hip_bfloat16*)alloc((size_t)Mrows * Esz * 2);
    __hip_bfloat16* wb_bf   = (__hip_bfloat16*)alloc((size_t)48 * Esz * 2);
    float* rowsum = (float*)alloc(Mrows * 4);
    float* u_buf  = (float*)alloc((size_t)Mrows * Ssz * 4);
    float* ct_buf = (float*)alloc((size_t)Mrows * Ssz * 4);
    float* ys_buf = (float*)alloc(Mrows * 4);
    __hip_bfloat16* y_bf = xc_bf;   // reuse: xc dead after bcd/gemm<1>

    hipMemsetAsync(rowsum, 0, Mrows * 4, stream);

    // conversions (single merged kernel)
    cvt_all<<<4608, 256, 0, stream>>>((const float4*)x, (const float4*)in_w,
                                      (const float4*)dt_w, (const float4*)out_w,
                                      (ushort4*)x_bf, (ushort4*)inw_bf,
                                      (ushort4*)dtw_bf, (ushort4*)outw_bf);
    pack_bcd<<<48 * Esz / 256, 256, 0, stream>>>(B_w, C_w, D_w, wb_bf);

    // GEMM1: xp = x @ in_w^T + in_b  (M=8192, N=4096, K=1024) -> bf16
    gemm_bt<0, 8, 8><<<dim3(4096 / 256, Mrows / 256), 256, 0, stream>>>(
        x_bf, inw_bf, in_b, Mrows, 4096, 1024, xp_bf, nullptr, nullptr, nullptr);

    // conv + SiLU -> xc
    conv_silu_k<<<(Mrows * Esz / 8) / 256, 256, 0, stream>>>(xp_bf, conv_w, conv_b, xc_bf);

    // GEMM2: softplus(xc @ dt_w^T + dt_b) row-sums (M=8192, N=2048, K=2048)
    gemm_bt<1, 8, 8><<<dim3(Esz / 256, Mrows / 256), 256, 0, stream>>>(
        xc_bf, dtw_bf, dt_b, Mrows, Esz, Esz, nullptr, rowsum, nullptr, nullptr);

    // B/C/D projections + u = Bt*Dt
    bcd_mfma<<<Mrows / 64, 256, 0, stream>>>(xc_bf, wb_bf, B_b, C_b, D_b, u_buf, ct_buf);

    // sequential scan (decay inline) -> ys
    scan_k<<<Bsz, 256, 0, stream>>>(rowsum, u_buf, ct_buf, ys_buf);

    // y = ys * silu(x_gate) -> bf16 (into xc buffer)
    ygate_k<<<(Mrows * Esz / 8) / 256, 256, 0, stream>>>(ys_buf, xp_bf, y_bf);

    // GEMM3: out = x + y @ out_w^T + out_b  (M=8192, N=1024, K=2048) -> fp32
    // 256x128 tiles keep the grid at 256 blocks (1/CU)
    gemm_bt<2, 8, 4><<<dim3(Dsz / 128, Mrows / 256), 256, 0, stream>>>(
        y_bf, outw_bf, out_b, Mrows, Dsz, Esz, nullptr, nullptr, x, out);
}

// Round 5
// 598.714 us; speedup vs baseline: 1.0321x; 1.0321x over previous
//
#include <hip/hip_runtime.h>
#include <hip/hip_bf16.h>

// Problem constants
#define Bsz 4
#define Tsz 2048
#define Dsz 1024
#define Ssz 16
#define Esz 2048
#define Mrows (Bsz*Tsz)        // 8192

typedef __attribute__((ext_vector_type(8))) short short8;
typedef __attribute__((ext_vector_type(4))) float floatx4;

__device__ __forceinline__ void async_ld16(const void* g, void* l) {
    __builtin_amdgcn_global_load_lds(
        (const __attribute__((address_space(1))) void*)g,
        (__attribute__((address_space(3))) void*)l,
        16, 0, 0);
}

__device__ __forceinline__ float sigmoidf_(float v) { return 1.f / (1.f + expf(-v)); }
__device__ __forceinline__ float bf2f(unsigned short u) {
    union { unsigned u32; float f; } c; c.u32 = (unsigned)u << 16; return c.f;
}

// s_waitcnt immediates (gfx9 encoding): vm[3:0]|exp[6:4]|lgkm[11:8]|vm[15:14]
#define WAIT_VM(N)   (0xF70 | (N))          // vmcnt(N), lgkm/exp no-wait
#define WAIT_LGKM(N) (0xC07F | ((N) << 8))  // lgkmcnt(N), vm/exp no-wait

// ---------------------------------------------------------------------------
// merged fp32 -> bf16 conversion for x, in_w, dt_w, out_w (float4 granules)
// ---------------------------------------------------------------------------
#define CVT_S0 2097152   // x:     8388608 f32 / 4
#define CVT_S1 3145728   // in_w: +4194304 / 4
#define CVT_S2 4194304   // dt_w: +4194304 / 4
#define CVT_S3 4718592   // out_w:+2097152 / 4
__global__ void cvt_all(const float4* __restrict__ x,  const float4* __restrict__ iw,
                        const float4* __restrict__ dw, const float4* __restrict__ ow,
                        ushort4* __restrict__ xb,  ushort4* __restrict__ iwb,
                        ushort4* __restrict__ dwb, ushort4* __restrict__ owb) {
    int i = blockIdx.x * blockDim.x + threadIdx.x;
    const int stride = gridDim.x * blockDim.x;
    for (; i < CVT_S3; i += stride) {
        float4 v; ushort4* dst; int j;
        if (i < CVT_S0)      { v = x [j = i];           dst = xb  + j; }
        else if (i < CVT_S1) { v = iw[j = i - CVT_S0];  dst = iwb + j; }
        else if (i < CVT_S2) { v = dw[j = i - CVT_S1];  dst = dwb + j; }
        else                 { v = ow[j = i - CVT_S2];  dst = owb + j; }
        __hip_bfloat16 a = __float2bfloat16(v.x), b = __float2bfloat16(v.y);
        __hip_bfloat16 c = __float2bfloat16(v.z), d = __float2bfloat16(v.w);
        ushort4 o;
        o.x = *(unsigned short*)&a; o.y = *(unsigned short*)&b;
        o.z = *(unsigned short*)&c; o.w = *(unsigned short*)&d;
        *dst = o;
    }
}

// ---------------------------------------------------------------------------
// bf16 GEMM: C[M,N] = A[M,K] @ Bw[N,K]^T (+bias).  128x128 block tile,
// 4 waves 2x2, each wave 64x64 via 4x4 mfma_f32_16x16x32_bf16.
// XOR-swizzled LDS (conflict-free frag reads, proven R4: conflicts=0).
// 1-barrier/ktile pipeline: 4-stage LDS ring (DMA prefetch distance 3,
// in-loop vmcnt(4) -- 2-iteration DMA window) + register-double-buffered
// fragments (ds_reads of tile kt+1 overlap MFMA burst of tile kt).
// Loop unrolled x2 so fragment buffer index is compile-time.
// MODE: 0 bf16 store, 1 softplus rowsum, 2 fp32 + resid.
// ---------------------------------------------------------------------------
template<int MODE, int TM, int TN>
__launch_bounds__(256, 2)
__global__ void gemm_bt(const __hip_bfloat16* __restrict__ A,
                        const __hip_bfloat16* __restrict__ Bw,
                        const float* __restrict__ bias,
                        int M, int N, int K,
                        __hip_bfloat16* __restrict__ outb,
                        float* __restrict__ rowsum,
                        const float* __restrict__ resid,
                        float* __restrict__ outf) {
    constexpr int BM = 32 * TM, BN = 32 * TN;             // 128 x 128
    constexpr int A_ISS = BM / 64, B_ISS = BN / 64;       // 2, 2
    constexpr int ABUF = BM * 32, BBUF = BN * 32;         // elements/stage

    __shared__ __align__(16) __hip_bfloat16 sA[4 * ABUF]; // 32 KB ring
    __shared__ __align__(16) __hip_bfloat16 sB[4 * BBUF]; // 32 KB ring

    const int tid  = threadIdx.x;
    const int wave = tid >> 6, lane = tid & 63;
    const int wm = wave >> 1, wn = wave & 1;
    const int q = lane >> 4, lr = lane & 15;
    const int m0 = blockIdx.y * BM, n0 = blockIdx.x * BN;

    floatx4 acc[TM][TN];
#pragma unroll
    for (int i = 0; i < TM; ++i)
#pragma unroll
        for (int j = 0; j < TN; ++j) acc[i][j] = (floatx4){0.f, 0.f, 0.f, 0.f};

    // staging map: chunk c = issue*256 + tid -> (row=c>>2, slot=c&3);
    // fetch global chunk slot^((row>>1)&3) so swizzled LDS slot holds it.
    const __hip_bfloat16* pa[A_ISS];
    const __hip_bfloat16* pb[B_ISS];
#pragma unroll
    for (int i = 0; i < A_ISS; ++i) {
        const int c = i * 256 + tid, row = c >> 2, slot = c & 3;
        pa[i] = A + (size_t)(m0 + row) * K + ((slot ^ ((row >> 1) & 3)) << 3);
    }
#pragma unroll
    for (int i = 0; i < B_ISS; ++i) {
        const int c = i * 256 + tid, row = c >> 2, slot = c & 3;
        pb[i] = Bw + (size_t)(n0 + row) * K + ((slot ^ ((row >> 1) & 3)) << 3);
    }

    // fragment LDS element-offsets within a stage (swizzled)
    int aoff[TM], boff[TN];
#pragma unroll
    for (int i = 0; i < TM; ++i) {
        const int r = wm * TM * 16 + i * 16 + lr;
        aoff[i] = r * 32 + ((q ^ ((r >> 1) & 3)) << 3);
    }
#pragma unroll
    for (int j = 0; j < TN; ++j) {
        const int r = wn * TN * 16 + j * 16 + lr;
        boff[j] = r * 32 + ((q ^ ((r >> 1) & 3)) << 3);
    }

    auto issue = [&](int koff, int st) {
#pragma unroll
        for (int i = 0; i < A_ISS; ++i)
            async_ld16(pa[i] + koff, &sA[st * ABUF + (i * 256 + wave * 64) * 8]);
#pragma unroll
        for (int i = 0; i < B_ISS; ++i)
            async_ld16(pb[i] + koff, &sB[st * BBUF + (i * 256 + wave * 64) * 8]);
    };

    const int nkt = K >> 5;       // 32 or 64, always even
    // preamble: stage tiles 0,1,2 into ring stages 0,1,2
    issue(0, 0);
    issue(32, 1);
    issue(64, 2);
    asm volatile("" ::: "memory");
    __builtin_amdgcn_s_waitcnt(WAIT_VM(8));    // tile 0 landed
    __builtin_amdgcn_s_barrier();
    asm volatile("" ::: "memory");

    short8 af0[TM], bf0[TN], af1[TM], bf1[TN];
#pragma unroll
    for (int i = 0; i < TM; ++i) af0[i] = *(const short8*)&sA[aoff[i]];
#pragma unroll
    for (int j = 0; j < TN; ++j) bf0[j] = *(const short8*)&sB[boff[j]];

    int koff = 96;                 // next tile to DMA (tile 3), clamped at tail

    // One pipeline step: MFMA tile kt from CUR regs; ds_read tile kt+1 into
    // NXT regs; DMA tile kt+3 into ring stage (kt+3)&3.
#define GEMM_STEP(kt, CURA, CURB, NXTA, NXTB)                                  \
    {                                                                          \
        asm volatile("" ::: "memory");                                         \
        __builtin_amdgcn_s_waitcnt(WAIT_VM(4));   /* tile kt+1 DMA done */     \
        __builtin_amdgcn_s_barrier();                                          \
        asm volatile("" ::: "memory");                                         \
        issue(koff, (kt + 3) & 3);                /* tile kt+3 */              \
        if ((kt) < nkt - 4) koff += 32;                                        \
        {                                                                      \
            const int rs_ = (kt + 1) & 3;                                      \
            const __hip_bfloat16* sa_ = &sA[rs_ * ABUF];                       \
            const __hip_bfloat16* sb_ = &sB[rs_ * BBUF];                       \
            _Pragma("unroll")                                                  \
            for (int i = 0; i < TM; ++i) NXTA[i] = *(const short8*)&sa_[aoff[i]]; \
            _Pragma("unroll")                                                  \
            for (int j = 0; j < TN; ++j) NXTB[j] = *(const short8*)&sb_[boff[j]]; \
        }                                                                      \
        asm volatile("" ::: "memory");                                         \
        __builtin_amdgcn_s_waitcnt(WAIT_LGKM(TM + TN)); /* CUR frags ready */  \
        asm volatile("" ::: "memory");                                         \
        _Pragma("unroll")                                                      \
        for (int i = 0; i < TM; ++i)                                           \
            _Pragma("unroll")                                                  \
            for (int j = 0; j < TN; ++j)                                       \
                acc[i][j] = __builtin_amdgcn_mfma_f32_16x16x32_bf16(           \
                    CURA[i], CURB[j], acc[i][j], 0, 0, 0);                     \
    }

    for (int kt = 0; kt < nkt; kt += 2) {
        GEMM_STEP(kt,     af0, bf0, af1, bf1);
        GEMM_STEP(kt + 1, af1, bf1, af0, bf0);
    }
#undef GEMM_STEP

    asm volatile("" ::: "memory");
    __builtin_amdgcn_s_waitcnt(WAIT_VM(0));    // drain tail DMA

    // epilogue: C/D layout col = lane&15, row = (lane>>4)*4 + reg
    if (MODE == 0) {
#pragma unroll
        for (int i = 0; i < TM; ++i) {
            const int row = m0 + wm * TM * 16 + i * 16 + q * 4;
#pragma unroll
            for (int j = 0; j < TN; ++j) {
                const int col = n0 + wn * TN * 16 + j * 16 + lr;
                const float bc = bias[col];
#pragma unroll
                for (int r = 0; r < 4; ++r)
                    outb[(size_t)(row + r) * N + col] = __float2bfloat16(acc[i][j][r] + bc);
            }
        }
    } else if (MODE == 1) {
#pragma unroll
        for (int i = 0; i < TM; ++i) {
            float rs[4] = {0.f, 0.f, 0.f, 0.f};
#pragma unroll
            for (int j = 0; j < TN; ++j) {
                const int col = n0 + wn * TN * 16 + j * 16 + lr;
                const float bc = bias[col];
#pragma unroll
                for (int r = 0; r < 4; ++r) {
                    float v = acc[i][j][r] + bc;
                    float sp = (v > 20.f) ? v : log1pf(expf(v));
                    rs[r] += sp;
                }
            }
#pragma unroll
            for (int r = 0; r < 4; ++r) {
                float v = rs[r];
                v += __shfl_xor(v, 1); v += __shfl_xor(v, 2);
                v += __shfl_xor(v, 4); v += __shfl_xor(v, 8);
                if (lr == 0)
                    atomicAdd(&rowsum[m0 + wm * TM * 16 + i * 16 + q * 4 + r], v);
            }
        }
    } else {
#pragma unroll
        for (int i = 0; i < TM; ++i) {
            const int row = m0 + wm * TM * 16 + i * 16 + q * 4;
#pragma unroll
            for (int j = 0; j < TN; ++j) {
                const int col = n0 + wn * TN * 16 + j * 16 + lr;
                const float bc = bias[col];
#pragma unroll
                for (int r = 0; r < 4; ++r) {
                    const size_t idx = (size_t)(row + r) * N + col;
                    outf[idx] = acc[i][j][r] + bc + resid[idx];
                }
            }
        }
    }
}

// ---------------------------------------------------------------------------
// depthwise conv (k=3, pad 1, along T) + bias + SiLU, 8 channels per thread.
// ---------------------------------------------------------------------------
__global__ void conv_silu_k(const __hip_bfloat16* __restrict__ xp,
                            const float* __restrict__ cw,
                            const float* __restrict__ cb,
                            __hip_bfloat16* __restrict__ xc) {
    const int idx8 = blockIdx.x * blockDim.x + threadIdx.x;
    const int e = (idx8 & (Esz / 8 - 1)) * 8;
    const int r = idx8 >> 8;
    const int t = r & (Tsz - 1);
    const unsigned short* row0 = (const unsigned short*)(xp + (size_t)r * (2 * Esz) + e);
    short8 vm1 = (t > 0)       ? *(const short8*)(row0 - 2 * Esz) : (short8){0,0,0,0,0,0,0,0};
    short8 v00 = *(const short8*)row0;
    short8 vp1 = (t < Tsz - 1) ? *(const short8*)(row0 + 2 * Esz) : (short8){0,0,0,0,0,0,0,0};
    short8 o;
#pragma unroll
    for (int k = 0; k < 8; ++k) {
        const int ek = e + k;
        float v = bf2f((unsigned short)vm1[k]) * cw[ek * 3 + 0]
                + bf2f((unsigned short)v00[k]) * cw[ek * 3 + 1]
                + bf2f((unsigned short)vp1[k]) * cw[ek * 3 + 2] + cb[ek];
        __hip_bfloat16 h = __float2bfloat16(v * sigmoidf_(v));
        o[k] = *(short*)&h;
    }
    *(short8*)(xc + (size_t)idx8 * 8) = o;
}

// ---------------------------------------------------------------------------
// pack B_w/C_w/D_w (each [16,2048] fp32) into Wb [48,2048] bf16
// ---------------------------------------------------------------------------
__global__ void pack_bcd(const float* __restrict__ Bw, const float* __restrict__ Cw,
                         const float* __restrict__ Dw, __hip_bfloat16* __restrict__ Wb) {
    const int idx = blockIdx.x * blockDim.x + threadIdx.x;
    if (idx >= 48 * Esz) return;
    const int row = idx >> 11, col = idx & (Esz - 1);
    float v;
    if (row < 16)      v = Bw[row * Esz + col];
    else if (row < 32) v = Cw[(row - 16) * Esz + col];
    else               v = Dw[(row - 32) * Esz + col];
    Wb[idx] = __float2bfloat16(v);
}

// ---------------------------------------------------------------------------
// B/C/D projections via MFMA skinny GEMM: xc[M,E] @ Wb[48,E]^T.
// ---------------------------------------------------------------------------
__launch_bounds__(256)
__global__ void bcd_mfma(const __hip_bfloat16* __restrict__ xc,
                         const __hip_bfloat16* __restrict__ Wb,
                         const float* __restrict__ Bb, const float* __restrict__ Cb,
                         const float* __restrict__ Db,
                         float* __restrict__ u, float* __restrict__ Ct) {
    __shared__ __align__(16) __hip_bfloat16 sA[64 * 32];
    __shared__ __align__(16) __hip_bfloat16 sW[48 * 32];
    const int tid = threadIdx.x;
    const int wave = tid >> 6, lane = tid & 63;
    const int q = lane >> 4, lr = lane & 15;
    const int m0 = blockIdx.x * 64;

    floatx4 acc[3];
#pragma unroll
    for (int j = 0; j < 3; ++j) acc[j] = (floatx4){0.f, 0.f, 0.f, 0.f};

    const int ra = wave * 16 + (lane >> 2);
    const int ca = (lane & 3) * 8;

    for (int kt = 0; kt < (Esz >> 5); ++kt) {
        const int k0 = kt << 5;
        __syncthreads();
        async_ld16(&xc[(size_t)(m0 + ra) * Esz + k0 + ca], &sA[wave * 512]);
        if (wave < 3)
            async_ld16(&Wb[(size_t)ra * Esz + k0 + ca], &sW[wave * 512]);
        __syncthreads();

        short8 af = *(const short8*)&sA[(wave * 16 + lr) * 32 + q * 8];
#pragma unroll
        for (int j = 0; j < 3; ++j) {
            short8 wf = *(const short8*)&sW[(j * 16 + lr) * 32 + q * 8];
            acc[j] = __builtin_amdgcn_mfma_f32_16x16x32_bf16(af, wf, acc[j], 0, 0, 0);
        }
    }

    const int row = m0 + wave * 16 + q * 4;
    const float bb = Bb[lr], cbv = Cb[lr], db = Db[lr];
#pragma unroll
    for (int r = 0; r < 4; ++r) {
        const float bt = acc[0][r] + bb;
        const float ct = acc[1][r] + cbv;
        const float dt = acc[2][r] + db;
        u [(size_t)(row + r) * Ssz + lr] = bt * dt;
        Ct[(size_t)(row + r) * Ssz + lr] = ct;
    }
}

// ---------------------------------------------------------------------------
// Sequential SSM scan (decay computed inline from rowsum).  One block/batch.
// ---------------------------------------------------------------------------
__global__ void scan_k(const float* __restrict__ rowsum, const float* __restrict__ u,
                       const float* __restrict__ Ct, float* __restrict__ ys) {
    const int b = blockIdx.x;
    const int tid = threadIdx.x;
    const int lane = tid & 63, wave = tid >> 6;
    __shared__ __align__(16) float su[256 * Ssz];
    __shared__ __align__(16) float sc[256 * Ssz];
    __shared__ float sp[256 * 17];
    __shared__ float sd[256];
    float st = 0.f;
    for (int t0 = 0; t0 < Tsz; t0 += 256) {
        __syncthreads();
        const float4* ub = (const float4*)(u  + ((size_t)b * Tsz + t0) * Ssz);
        const float4* cb = (const float4*)(Ct + ((size_t)b * Tsz + t0) * Ssz);
#pragma unroll
        for (int i = 0; i < 4; ++i) {
            ((float4*)su)[tid + i * 256] = ub[tid + i * 256];
            ((float4*)sc)[tid + i * 256] = cb[tid + i * 256];
        }
        {
            const float m = rowsum[b * Tsz + t0 + tid] * (1.f / (float)Esz);
            sd[tid] = expf(fminf(fmaxf(-m, -10.f), 10.f));
        }
        __syncthreads();
        if (wave == 0 && lane < 16) {
#pragma unroll 8
            for (int i = 0; i < 256; ++i) {
                st = st * sd[i] + su[i * Ssz + lane];
                sp[i * 17 + lane] = sc[i * Ssz + lane] * st;
            }
        }
        __syncthreads();
        float s = 0.f;
#pragma unroll
        for (int j = 0; j < 16; ++j) s += sp[tid * 17 + j];
        ys[b * Tsz + t0 + tid] = s;
    }
}

// ---------------------------------------------------------------------------
// y[r,e] = ys[r] * silu(x_gate[r,e]), 8 per thread; gate = xp cols [E,2E).
// ---------------------------------------------------------------------------
__global__ void ygate_k(const float* __restrict__ ys, const __hip_bfloat16* __restrict__ xp,
                        __hip_bfloat16* __restrict__ y) {
    const int idx8 = blockIdx.x * blockDim.x + threadIdx.x;
    const int e = (idx8 & (Esz / 8 - 1)) * 8;
    const int r = idx8 >> 8;
    const float yr = ys[r];
    short8 g = *(const short8*)(xp + (size_t)r * (2 * Esz) + Esz + e);
    short8 o;
#pragma unroll
    for (int k = 0; k < 8; ++k) {
        const float gv = bf2f((unsigned short)g[k]);
        __hip_bfloat16 h = __float2bfloat16(yr * gv * sigmoidf_(gv));
        o[k] = *(short*)&h;
    }
    *(short8*)(y + (size_t)idx8 * 8) = o;
}

// ---------------------------------------------------------------------------
extern "C" void kernel_launch(void* const* d_in, const int* in_sizes, int n_in,
                              void* d_out, int out_size, void* d_ws, size_t ws_size,
                              hipStream_t stream) {
    const float* x      = (const float*)d_in[0];
    const float* in_w   = (const float*)d_in[1];
    const float* in_b   = (const float*)d_in[2];
    const float* conv_w = (const float*)d_in[3];
    const float* conv_b = (const float*)d_in[4];
    const float* dt_w   = (const float*)d_in[5];
    const float* dt_b   = (const float*)d_in[6];
    const float* B_w    = (const float*)d_in[7];
    const float* B_b    = (const float*)d_in[8];
    const float* C_w    = (const float*)d_in[9];
    const float* C_b    = (const float*)d_in[10];
    const float* D_w    = (const float*)d_in[11];
    const float* D_b    = (const float*)d_in[12];
    const float* out_w  = (const float*)d_in[13];
    const float* out_b  = (const float*)d_in[14];
    float* out = (float*)d_out;

    char* ws = (char*)d_ws;
    auto alloc = [&](size_t bytes) {
        char* p = ws;
        ws += (bytes + 255) & ~(size_t)255;
        return p;
    };
    __hip_bfloat16* x_bf    = (__hip_bfloat16*)alloc((size_t)Mrows * Dsz * 2);
    __hip_bfloat16* inw_bf  = (__hip_bfloat16*)alloc((size_t)2 * Esz * Dsz * 2);
    __hip_bfloat16* dtw_bf  = (__hip_bfloat16*)alloc((size_t)Esz * Esz * 2);
    __hip_bfloat16* outw_bf = (__hip_bfloat16*)alloc((size_t)Dsz * Esz * 2);
    __hip_bfloat16* xp_bf   = (__hip_bfloat16*)alloc((size_t)Mrows * 2 * Esz * 2);
    __hip_bfloat16* xc_bf   = (__hip_bfloat16*)alloc((size_t)Mrows * Esz * 2);
    __hip_bfloat16* wb_bf   = (__hip_bfloat16*)alloc((size_t)48 * Esz * 2);
    float* rowsum = (float*)alloc(Mrows * 4);
    float* u_buf  = (float*)alloc((size_t)Mrows * Ssz * 4);
    float* ct_buf = (float*)alloc((size_t)Mrows * Ssz * 4);
    float* ys_buf = (float*)alloc(Mrows * 4);
    __hip_bfloat16* y_bf = xc_bf;   // reuse: xc dead after bcd/gemm<1>

    hipMemsetAsync(rowsum, 0, Mrows * 4, stream);

    // conversions (single merged kernel)
    cvt_all<<<4608, 256, 0, stream>>>((const float4*)x, (const float4*)in_w,
                                      (const float4*)dt_w, (const float4*)out_w,
                                      (ushort4*)x_bf, (ushort4*)inw_bf,
                                      (ushort4*)dtw_bf, (ushort4*)outw_bf);
    pack_bcd<<<48 * Esz / 256, 256, 0, stream>>>(B_w, C_w, D_w, wb_bf);

    // GEMM1: xp = x @ in_w^T + in_b  (M=8192, N=4096, K=1024) -> bf16
    gemm_bt<0, 4, 4><<<dim3(4096 / 128, Mrows / 128), 256, 0, stream>>>(
        x_bf, inw_bf, in_b, Mrows, 4096, 1024, xp_bf, nullptr, nullptr, nullptr);

    // conv + SiLU -> xc
    conv_silu_k<<<(Mrows * Esz / 8) / 256, 256, 0, stream>>>(xp_bf, conv_w, conv_b, xc_bf);

    // GEMM2: softplus(xc @ dt_w^T + dt_b) row-sums (M=8192, N=2048, K=2048)
    gemm_bt<1, 4, 4><<<dim3(Esz / 128, Mrows / 128), 256, 0, stream>>>(
        xc_bf, dtw_bf, dt_b, Mrows, Esz, Esz, nullptr, rowsum, nullptr, nullptr);

    // B/C/D projections + u = Bt*Dt
    bcd_mfma<<<Mrows / 64, 256, 0, stream>>>(xc_bf, wb_bf, B_b, C_b, D_b, u_buf, ct_buf);

    // sequential scan (decay inline) -> ys
    scan_k<<<Bsz, 256, 0, stream>>>(rowsum, u_buf, ct_buf, ys_buf);

    // y = ys * silu(x_gate) -> bf16 (into xc buffer)
    ygate_k<<<(Mrows * Esz / 8) / 256, 256, 0, stream>>>(ys_buf, xp_bf, y_bf);

    // GEMM3: out = x + y @ out_w^T + out_b  (M=8192, N=1024, K=2048) -> fp32
    gemm_bt<2, 4, 4><<<dim3(Dsz / 128, Mrows / 128), 256, 0, stream>>>(
        y_bf, outw_bf, out_b, Mrows, Dsz, Esz, nullptr, nullptr, x, out);
}

// Round 6
// 525.301 us; speedup vs baseline: 1.1764x; 1.1398x over previous
//
#include <hip/hip_runtime.h>
#include <hip/hip_bf16.h>

// Problem constants
#define Bsz 4
#define Tsz 2048
#define Dsz 1024
#define Ssz 16
#define Esz 2048
#define Mrows (Bsz*Tsz)        // 8192

typedef __attribute__((ext_vector_type(8))) short short8;
typedef __attribute__((ext_vector_type(4))) float floatx4;

__device__ __forceinline__ void async_ld16(const void* g, void* l) {
    __builtin_amdgcn_global_load_lds(
        (const __attribute__((address_space(1))) void*)g,
        (__attribute__((address_space(3))) void*)l,
        16, 0, 0);
}

__device__ __forceinline__ float sigmoidf_(float v) { return 1.f / (1.f + expf(-v)); }
__device__ __forceinline__ float bf2f(unsigned short u) {
    union { unsigned u32; float f; } c; c.u32 = (unsigned)u << 16; return c.f;
}

// s_waitcnt immediates (gfx9 encoding): vm[3:0]|exp[6:4]|lgkm[11:8]|vm[15:14]
#define WAIT_VM(N)   (0xF70 | (N))          // vmcnt(N), lgkm/exp no-wait
#define WAIT_LGKM(N) (0xC07F | ((N) << 8))  // lgkmcnt(N), vm/exp no-wait

// ---------------------------------------------------------------------------
// merged fp32 -> bf16 conversion for x, in_w, dt_w, out_w (float4 granules)
// ---------------------------------------------------------------------------
#define CVT_S0 2097152   // x:     8388608 f32 / 4
#define CVT_S1 3145728   // in_w: +4194304 / 4
#define CVT_S2 4194304   // dt_w: +4194304 / 4
#define CVT_S3 4718592   // out_w:+2097152 / 4
__global__ void cvt_all(const float4* __restrict__ x,  const float4* __restrict__ iw,
                        const float4* __restrict__ dw, const float4* __restrict__ ow,
                        ushort4* __restrict__ xb,  ushort4* __restrict__ iwb,
                        ushort4* __restrict__ dwb, ushort4* __restrict__ owb) {
    int i = blockIdx.x * blockDim.x + threadIdx.x;
    const int stride = gridDim.x * blockDim.x;
    for (; i < CVT_S3; i += stride) {
        float4 v; ushort4* dst; int j;
        if (i < CVT_S0)      { v = x [j = i];           dst = xb  + j; }
        else if (i < CVT_S1) { v = iw[j = i - CVT_S0];  dst = iwb + j; }
        else if (i < CVT_S2) { v = dw[j = i - CVT_S1];  dst = dwb + j; }
        else                 { v = ow[j = i - CVT_S2];  dst = owb + j; }
        __hip_bfloat16 a = __float2bfloat16(v.x), b = __float2bfloat16(v.y);
        __hip_bfloat16 c = __float2bfloat16(v.z), d = __float2bfloat16(v.w);
        ushort4 o;
        o.x = *(unsigned short*)&a; o.y = *(unsigned short*)&b;
        o.z = *(unsigned short*)&c; o.w = *(unsigned short*)&d;
        *dst = o;
    }
}

// ---------------------------------------------------------------------------
// bf16 GEMM: C[M,N] = A[M,K] @ Bw[N,K]^T (+bias).  128x128 block tile,
// 4 waves 2x2, each wave 64x64 via 4x4 mfma_f32_16x16x32_bf16.
// R3's best-measured 2-stage / 2-barrier / dist-2-prefetch K-loop
// (32 KB LDS -> occupancy-friendly), plus:
//  - XOR-swizzled LDS (R4-proven: SQ_LDS_BANK_CONFLICT 8.4M -> 0)
//  - __launch_bounds__(256,3): cap regs at 170 so 3 blocks/CU fit
//  - XCD-aware block remap: each XCD owns a contiguous M-stripe so its
//    A-stripe (4 MB at gy=64) lives in its private L2.
// MODE: 0 bf16 store, 1 softplus rowsum, 2 fp32 + resid.
// ---------------------------------------------------------------------------
template<int MODE, int TM, int TN>
__launch_bounds__(256, 3)
__global__ void gemm_bt(const __hip_bfloat16* __restrict__ A,
                        const __hip_bfloat16* __restrict__ Bw,
                        const float* __restrict__ bias,
                        int M, int N, int K,
                        __hip_bfloat16* __restrict__ outb,
                        float* __restrict__ rowsum,
                        const float* __restrict__ resid,
                        float* __restrict__ outf) {
    constexpr int BM = 32 * TM, BN = 32 * TN;             // 128 x 128
    constexpr int A_ISS = BM / 64, B_ISS = BN / 64;       // 2, 2
    constexpr int NW = A_ISS + B_ISS;                     // 4 loads/wave/tile
    constexpr int ABUF = BM * 32, BBUF = BN * 32;         // elements/stage

    __shared__ __align__(16) __hip_bfloat16 sA[2 * ABUF]; // 16 KB
    __shared__ __align__(16) __hip_bfloat16 sB[2 * BBUF]; // 16 KB

    const int tid  = threadIdx.x;
    const int wave = tid >> 6, lane = tid & 63;
    const int wm = wave >> 1, wn = wave & 1;
    const int q = lane >> 4, lr = lane & 15;

    // XCD-aware remap: hw assigns flat%8 -> XCD (round-robin).  Give each
    // XCD a contiguous stripe of M-tiles (gy/8), iterate M within stripe
    // fastest so the A-stripe stays hot in that XCD's L2.
    const int gx = gridDim.x, gy = gridDim.y;
    const int flat = blockIdx.y * gx + blockIdx.x;
    const int stripe = gy >> 3;                  // gy always 64 here -> 8
    const int xcd = flat & 7, local = flat >> 3;
    const int mt = xcd * stripe + (local % stripe);
    const int nt = local / stripe;
    const int m0 = mt * BM, n0 = nt * BN;

    floatx4 acc[TM][TN];
#pragma unroll
    for (int i = 0; i < TM; ++i)
#pragma unroll
        for (int j = 0; j < TN; ++j) acc[i][j] = (floatx4){0.f, 0.f, 0.f, 0.f};

    // staging map: chunk c = issue*256 + tid -> (row=c>>2, slot=c&3);
    // fetch global chunk slot^((row>>1)&3) so swizzled LDS slot holds it.
    const __hip_bfloat16* pa[A_ISS];
    const __hip_bfloat16* pb[B_ISS];
#pragma unroll
    for (int i = 0; i < A_ISS; ++i) {
        const int c = i * 256 + tid, row = c >> 2, slot = c & 3;
        pa[i] = A + (size_t)(m0 + row) * K + ((slot ^ ((row >> 1) & 3)) << 3);
    }
#pragma unroll
    for (int i = 0; i < B_ISS; ++i) {
        const int c = i * 256 + tid, row = c >> 2, slot = c & 3;
        pb[i] = Bw + (size_t)(n0 + row) * K + ((slot ^ ((row >> 1) & 3)) << 3);
    }

    // fragment LDS element-offsets within a stage (swizzled)
    int aoff[TM], boff[TN];
#pragma unroll
    for (int i = 0; i < TM; ++i) {
        const int r = wm * TM * 16 + i * 16 + lr;
        aoff[i] = r * 32 + ((q ^ ((r >> 1) & 3)) << 3);
    }
#pragma unroll
    for (int j = 0; j < TN; ++j) {
        const int r = wn * TN * 16 + j * 16 + lr;
        boff[j] = r * 32 + ((q ^ ((r >> 1) & 3)) << 3);
    }

    auto issue = [&](int koff, int st) {
#pragma unroll
        for (int i = 0; i < A_ISS; ++i)
            async_ld16(pa[i] + koff, &sA[st * ABUF + (i * 256 + wave * 64) * 8]);
#pragma unroll
        for (int i = 0; i < B_ISS; ++i)
            async_ld16(pb[i] + koff, &sB[st * BBUF + (i * 256 + wave * 64) * 8]);
    };

    const int nkt = K >> 5;
    issue(0, 0);          // tile 0 -> stage 0
    issue(32, 1);         // tile 1 -> stage 1
    int koff = 64;        // next tile to DMA (clamped at tail)

    for (int kt = 0; kt < nkt; ++kt) {
        const int cur = kt & 1;
        asm volatile("" ::: "memory");
        __builtin_amdgcn_s_waitcnt(WAIT_VM(NW));  // tile kt landed, kt+1 in flight
        __builtin_amdgcn_s_barrier();
        asm volatile("" ::: "memory");

        const __hip_bfloat16* sa = &sA[cur * ABUF];
        const __hip_bfloat16* sb = &sB[cur * BBUF];
        short8 af[TM], bfv[TN];
#pragma unroll
        for (int i = 0; i < TM; ++i) af[i]  = *(const short8*)&sa[aoff[i]];
#pragma unroll
        for (int j = 0; j < TN; ++j) bfv[j] = *(const short8*)&sb[boff[j]];

        asm volatile("" ::: "memory");
        __builtin_amdgcn_s_waitcnt(WAIT_LGKM(0)); // frags landed
        __builtin_amdgcn_s_barrier();             // stage cur reusable
        asm volatile("" ::: "memory");

        issue(koff, cur);                          // tile kt+2 -> stage cur
        if (kt < nkt - 3) koff += 32;              // clamp keeps vmcnt uniform

#pragma unroll
        for (int i = 0; i < TM; ++i)
#pragma unroll
            for (int j = 0; j < TN; ++j)
                acc[i][j] = __builtin_amdgcn_mfma_f32_16x16x32_bf16(af[i], bfv[j], acc[i][j], 0, 0, 0);
    }
    asm volatile("" ::: "memory");
    __builtin_amdgcn_s_waitcnt(WAIT_VM(0));       // drain tail DMA

    // epilogue: C/D layout col = lane&15, row = (lane>>4)*4 + reg
    if (MODE == 0) {
#pragma unroll
        for (int i = 0; i < TM; ++i) {
            const int row = m0 + wm * TM * 16 + i * 16 + q * 4;
#pragma unroll
            for (int j = 0; j < TN; ++j) {
                const int col = n0 + wn * TN * 16 + j * 16 + lr;
                const float bc = bias[col];
#pragma unroll
                for (int r = 0; r < 4; ++r)
                    outb[(size_t)(row + r) * N + col] = __float2bfloat16(acc[i][j][r] + bc);
            }
        }
    } else if (MODE == 1) {
#pragma unroll
        for (int i = 0; i < TM; ++i) {
            float rs[4] = {0.f, 0.f, 0.f, 0.f};
#pragma unroll
            for (int j = 0; j < TN; ++j) {
                const int col = n0 + wn * TN * 16 + j * 16 + lr;
                const float bc = bias[col];
#pragma unroll
                for (int r = 0; r < 4; ++r) {
                    float v = acc[i][j][r] + bc;
                    float sp = (v > 20.f) ? v : log1pf(expf(v));
                    rs[r] += sp;
                }
            }
#pragma unroll
            for (int r = 0; r < 4; ++r) {
                float v = rs[r];
                v += __shfl_xor(v, 1); v += __shfl_xor(v, 2);
                v += __shfl_xor(v, 4); v += __shfl_xor(v, 8);
                if (lr == 0)
                    atomicAdd(&rowsum[m0 + wm * TM * 16 + i * 16 + q * 4 + r], v);
            }
        }
    } else {
#pragma unroll
        for (int i = 0; i < TM; ++i) {
            const int row = m0 + wm * TM * 16 + i * 16 + q * 4;
#pragma unroll
            for (int j = 0; j < TN; ++j) {
                const int col = n0 + wn * TN * 16 + j * 16 + lr;
                const float bc = bias[col];
#pragma unroll
                for (int r = 0; r < 4; ++r) {
                    const size_t idx = (size_t)(row + r) * N + col;
                    outf[idx] = acc[i][j][r] + bc + resid[idx];
                }
            }
        }
    }
}

// ---------------------------------------------------------------------------
// depthwise conv (k=3, pad 1, along T) + bias + SiLU, 8 channels per thread.
// ---------------------------------------------------------------------------
__global__ void conv_silu_k(const __hip_bfloat16* __restrict__ xp,
                            const float* __restrict__ cw,
                            const float* __restrict__ cb,
                            __hip_bfloat16* __restrict__ xc) {
    const int idx8 = blockIdx.x * blockDim.x + threadIdx.x;
    const int e = (idx8 & (Esz / 8 - 1)) * 8;
    const int r = idx8 >> 8;
    const int t = r & (Tsz - 1);
    const unsigned short* row0 = (const unsigned short*)(xp + (size_t)r * (2 * Esz) + e);
    short8 vm1 = (t > 0)       ? *(const short8*)(row0 - 2 * Esz) : (short8){0,0,0,0,0,0,0,0};
    short8 v00 = *(const short8*)row0;
    short8 vp1 = (t < Tsz - 1) ? *(const short8*)(row0 + 2 * Esz) : (short8){0,0,0,0,0,0,0,0};
    short8 o;
#pragma unroll
    for (int k = 0; k < 8; ++k) {
        const int ek = e + k;
        float v = bf2f((unsigned short)vm1[k]) * cw[ek * 3 + 0]
                + bf2f((unsigned short)v00[k]) * cw[ek * 3 + 1]
                + bf2f((unsigned short)vp1[k]) * cw[ek * 3 + 2] + cb[ek];
        __hip_bfloat16 h = __float2bfloat16(v * sigmoidf_(v));
        o[k] = *(short*)&h;
    }
    *(short8*)(xc + (size_t)idx8 * 8) = o;
}

// ---------------------------------------------------------------------------
// pack B_w/C_w/D_w (each [16,2048] fp32) into Wb [48,2048] bf16
// ---------------------------------------------------------------------------
__global__ void pack_bcd(const float* __restrict__ Bw, const float* __restrict__ Cw,
                         const float* __restrict__ Dw, __hip_bfloat16* __restrict__ Wb) {
    const int idx = blockIdx.x * blockDim.x + threadIdx.x;
    if (idx >= 48 * Esz) return;
    const int row = idx >> 11, col = idx & (Esz - 1);
    float v;
    if (row < 16)      v = Bw[row * Esz + col];
    else if (row < 32) v = Cw[(row - 16) * Esz + col];
    else               v = Dw[(row - 32) * Esz + col];
    Wb[idx] = __float2bfloat16(v);
}

// ---------------------------------------------------------------------------
// B/C/D projections via MFMA skinny GEMM: xc[M,E] @ Wb[48,E]^T.
// ---------------------------------------------------------------------------
__launch_bounds__(256)
__global__ void bcd_mfma(const __hip_bfloat16* __restrict__ xc,
                         const __hip_bfloat16* __restrict__ Wb,
                         const float* __restrict__ Bb, const float* __restrict__ Cb,
                         const float* __restrict__ Db,
                         float* __restrict__ u, float* __restrict__ Ct) {
    __shared__ __align__(16) __hip_bfloat16 sA[64 * 32];
    __shared__ __align__(16) __hip_bfloat16 sW[48 * 32];
    const int tid = threadIdx.x;
    const int wave = tid >> 6, lane = tid & 63;
    const int q = lane >> 4, lr = lane & 15;
    const int m0 = blockIdx.x * 64;

    floatx4 acc[3];
#pragma unroll
    for (int j = 0; j < 3; ++j) acc[j] = (floatx4){0.f, 0.f, 0.f, 0.f};

    const int ra = wave * 16 + (lane >> 2);
    const int ca = (lane & 3) * 8;

    for (int kt = 0; kt < (Esz >> 5); ++kt) {
        const int k0 = kt << 5;
        __syncthreads();
        async_ld16(&xc[(size_t)(m0 + ra) * Esz + k0 + ca], &sA[wave * 512]);
        if (wave < 3)
            async_ld16(&Wb[(size_t)ra * Esz + k0 + ca], &sW[wave * 512]);
        __syncthreads();

        short8 af = *(const short8*)&sA[(wave * 16 + lr) * 32 + q * 8];
#pragma unroll
        for (int j = 0; j < 3; ++j) {
            short8 wf = *(const short8*)&sW[(j * 16 + lr) * 32 + q * 8];
            acc[j] = __builtin_amdgcn_mfma_f32_16x16x32_bf16(af, wf, acc[j], 0, 0, 0);
        }
    }

    const int row = m0 + wave * 16 + q * 4;
    const float bb = Bb[lr], cbv = Cb[lr], db = Db[lr];
#pragma unroll
    for (int r = 0; r < 4; ++r) {
        const float bt = acc[0][r] + bb;
        const float ct = acc[1][r] + cbv;
        const float dt = acc[2][r] + db;
        u [(size_t)(row + r) * Ssz + lr] = bt * dt;
        Ct[(size_t)(row + r) * Ssz + lr] = ct;
    }
}

// ---------------------------------------------------------------------------
// Sequential SSM scan (decay computed inline from rowsum).  One block/batch.
// ---------------------------------------------------------------------------
__global__ void scan_k(const float* __restrict__ rowsum, const float* __restrict__ u,
                       const float* __restrict__ Ct, float* __restrict__ ys) {
    const int b = blockIdx.x;
    const int tid = threadIdx.x;
    const int lane = tid & 63, wave = tid >> 6;
    __shared__ __align__(16) float su[256 * Ssz];
    __shared__ __align__(16) float sc[256 * Ssz];
    __shared__ float sp[256 * 17];
    __shared__ float sd[256];
    float st = 0.f;
    for (int t0 = 0; t0 < Tsz; t0 += 256) {
        __syncthreads();
        const float4* ub = (const float4*)(u  + ((size_t)b * Tsz + t0) * Ssz);
        const float4* cb = (const float4*)(Ct + ((size_t)b * Tsz + t0) * Ssz);
#pragma unroll
        for (int i = 0; i < 4; ++i) {
            ((float4*)su)[tid + i * 256] = ub[tid + i * 256];
            ((float4*)sc)[tid + i * 256] = cb[tid + i * 256];
        }
        {
            const float m = rowsum[b * Tsz + t0 + tid] * (1.f / (float)Esz);
            sd[tid] = expf(fminf(fmaxf(-m, -10.f), 10.f));
        }
        __syncthreads();
        if (wave == 0 && lane < 16) {
#pragma unroll 8
            for (int i = 0; i < 256; ++i) {
                st = st * sd[i] + su[i * Ssz + lane];
                sp[i * 17 + lane] = sc[i * Ssz + lane] * st;
            }
        }
        __syncthreads();
        float s = 0.f;
#pragma unroll
        for (int j = 0; j < 16; ++j) s += sp[tid * 17 + j];
        ys[b * Tsz + t0 + tid] = s;
    }
}

// ---------------------------------------------------------------------------
// y[r,e] = ys[r] * silu(x_gate[r,e]), 8 per thread; gate = xp cols [E,2E).
// ---------------------------------------------------------------------------
__global__ void ygate_k(const float* __restrict__ ys, const __hip_bfloat16* __restrict__ xp,
                        __hip_bfloat16* __restrict__ y) {
    const int idx8 = blockIdx.x * blockDim.x + threadIdx.x;
    const int e = (idx8 & (Esz / 8 - 1)) * 8;
    const int r = idx8 >> 8;
    const float yr = ys[r];
    short8 g = *(const short8*)(xp + (size_t)r * (2 * Esz) + Esz + e);
    short8 o;
#pragma unroll
    for (int k = 0; k < 8; ++k) {
        const float gv = bf2f((unsigned short)g[k]);
        __hip_bfloat16 h = __float2bfloat16(yr * gv * sigmoidf_(gv));
        o[k] = *(short*)&h;
    }
    *(short8*)(y + (size_t)idx8 * 8) = o;
}

// ---------------------------------------------------------------------------
extern "C" void kernel_launch(void* const* d_in, const int* in_sizes, int n_in,
                              void* d_out, int out_size, void* d_ws, size_t ws_size,
                              hipStream_t stream) {
    const float* x      = (const float*)d_in[0];
    const float* in_w   = (const float*)d_in[1];
    const float* in_b   = (const float*)d_in[2];
    const float* conv_w = (const float*)d_in[3];
    const float* conv_b = (const float*)d_in[4];
    const float* dt_w   = (const float*)d_in[5];
    const float* dt_b   = (const float*)d_in[6];
    const float* B_w    = (const float*)d_in[7];
    const float* B_b    = (const float*)d_in[8];
    const float* C_w    = (const float*)d_in[9];
    const float* C_b    = (const float*)d_in[10];
    const float* D_w    = (const float*)d_in[11];
    const float* D_b    = (const float*)d_in[12];
    const float* out_w  = (const float*)d_in[13];
    const float* out_b  = (const float*)d_in[14];
    float* out = (float*)d_out;

    char* ws = (char*)d_ws;
    auto alloc = [&](size_t bytes) {
        char* p = ws;
        ws += (bytes + 255) & ~(size_t)255;
        return p;
    };
    __hip_bfloat16* x_bf    = (__hip_bfloat16*)alloc((size_t)Mrows * Dsz * 2);
    __hip_bfloat16* inw_bf  = (__hip_bfloat16*)alloc((size_t)2 * Esz * Dsz * 2);
    __hip_bfloat16* dtw_bf  = (__hip_bfloat16*)alloc((size_t)Esz * Esz * 2);
    __hip_bfloat16* outw_bf = (__hip_bfloat16*)alloc((size_t)Dsz * Esz * 2);
    __hip_bfloat16* xp_bf   = (__hip_bfloat16*)alloc((size_t)Mrows * 2 * Esz * 2);
    __hip_bfloat16* xc_bf   = (__hip_bfloat16*)alloc((size_t)Mrows * Esz * 2);
    __hip_bfloat16* wb_bf   = (__hip_bfloat16*)alloc((size_t)48 * Esz * 2);
    float* rowsum = (float*)alloc(Mrows * 4);
    float* u_buf  = (float*)alloc((size_t)Mrows * Ssz * 4);
    float* ct_buf = (float*)alloc((size_t)Mrows * Ssz * 4);
    float* ys_buf = (float*)alloc(Mrows * 4);
    __hip_bfloat16* y_bf = xc_bf;   // reuse: xc dead after bcd/gemm<1>

    hipMemsetAsync(rowsum, 0, Mrows * 4, stream);

    // conversions (single merged kernel)
    cvt_all<<<4608, 256, 0, stream>>>((const float4*)x, (const float4*)in_w,
                                      (const float4*)dt_w, (const float4*)out_w,
                                      (ushort4*)x_bf, (ushort4*)inw_bf,
                                      (ushort4*)dtw_bf, (ushort4*)outw_bf);
    pack_bcd<<<48 * Esz / 256, 256, 0, stream>>>(B_w, C_w, D_w, wb_bf);

    // GEMM1: xp = x @ in_w^T + in_b  (M=8192, N=4096, K=1024) -> bf16
    gemm_bt<0, 4, 4><<<dim3(4096 / 128, Mrows / 128), 256, 0, stream>>>(
        x_bf, inw_bf, in_b, Mrows, 4096, 1024, xp_bf, nullptr, nullptr, nullptr);

    // conv + SiLU -> xc
    conv_silu_k<<<(Mrows * Esz / 8) / 256, 256, 0, stream>>>(xp_bf, conv_w, conv_b, xc_bf);

    // GEMM2: softplus(xc @ dt_w^T + dt_b) row-sums (M=8192, N=2048, K=2048)
    gemm_bt<1, 4, 4><<<dim3(Esz / 128, Mrows / 128), 256, 0, stream>>>(
        xc_bf, dtw_bf, dt_b, Mrows, Esz, Esz, nullptr, rowsum, nullptr, nullptr);

    // B/C/D projections + u = Bt*Dt
    bcd_mfma<<<Mrows / 64, 256, 0, stream>>>(xc_bf, wb_bf, B_b, C_b, D_b, u_buf, ct_buf);

    // sequential scan (decay inline) -> ys
    scan_k<<<Bsz, 256, 0, stream>>>(rowsum, u_buf, ct_buf, ys_buf);

    // y = ys * silu(x_gate) -> bf16 (into xc buffer)
    ygate_k<<<(Mrows * Esz / 8) / 256, 256, 0, stream>>>(ys_buf, xp_bf, y_bf);

    // GEMM3: out = x + y @ out_w^T + out_b  (M=8192, N=1024, K=2048) -> fp32
    gemm_bt<2, 4, 4><<<dim3(Dsz / 128, Mrows / 128), 256, 0, stream>>>(
        y_bf, outw_bf, out_b, Mrows, Dsz, Esz, nullptr, nullptr, x, out);
}

// Round 7
// 514.197 us; speedup vs baseline: 1.2018x; 1.0216x over previous
//
#include <hip/hip_runtime.h>
#include <hip/hip_bf16.h>

// Problem constants
#define Bsz 4
#define Tsz 2048
#define Dsz 1024
#define Ssz 16
#define Esz 2048
#define Mrows (Bsz*Tsz)        // 8192

typedef __attribute__((ext_vector_type(8))) short short8;
typedef __attribute__((ext_vector_type(4))) float floatx4;

__device__ __forceinline__ void async_ld16(const void* g, void* l) {
    __builtin_amdgcn_global_load_lds(
        (const __attribute__((address_space(1))) void*)g,
        (__attribute__((address_space(3))) void*)l,
        16, 0, 0);
}

__device__ __forceinline__ float sigmoidf_(float v) { return 1.f / (1.f + expf(-v)); }
__device__ __forceinline__ float bf2f(unsigned short u) {
    union { unsigned u32; float f; } c; c.u32 = (unsigned)u << 16; return c.f;
}

// s_waitcnt immediates (gfx9 encoding): vm[3:0]|exp[6:4]|lgkm[11:8]|vm[15:14]
#define WAIT_VM(N)   (0xF70 | (N))          // vmcnt(N), lgkm/exp no-wait
#define WAIT_LGKM(N) (0xC07F | ((N) << 8))  // lgkmcnt(N), vm/exp no-wait

// ---------------------------------------------------------------------------
// merged fp32 -> bf16 conversion for x, in_w, dt_w, out_w (float4 granules)
// ---------------------------------------------------------------------------
#define CVT_S0 2097152   // x:     8388608 f32 / 4
#define CVT_S1 3145728   // in_w: +4194304 / 4
#define CVT_S2 4194304   // dt_w: +4194304 / 4
#define CVT_S3 4718592   // out_w:+2097152 / 4
__global__ void cvt_all(const float4* __restrict__ x,  const float4* __restrict__ iw,
                        const float4* __restrict__ dw, const float4* __restrict__ ow,
                        ushort4* __restrict__ xb,  ushort4* __restrict__ iwb,
                        ushort4* __restrict__ dwb, ushort4* __restrict__ owb) {
    int i = blockIdx.x * blockDim.x + threadIdx.x;
    const int stride = gridDim.x * blockDim.x;
    for (; i < CVT_S3; i += stride) {
        float4 v; ushort4* dst; int j;
        if (i < CVT_S0)      { v = x [j = i];           dst = xb  + j; }
        else if (i < CVT_S1) { v = iw[j = i - CVT_S0];  dst = iwb + j; }
        else if (i < CVT_S2) { v = dw[j = i - CVT_S1];  dst = dwb + j; }
        else                 { v = ow[j = i - CVT_S2];  dst = owb + j; }
        __hip_bfloat16 a = __float2bfloat16(v.x), b = __float2bfloat16(v.y);
        __hip_bfloat16 c = __float2bfloat16(v.z), d = __float2bfloat16(v.w);
        ushort4 o;
        o.x = *(unsigned short*)&a; o.y = *(unsigned short*)&b;
        o.z = *(unsigned short*)&c; o.w = *(unsigned short*)&d;
        *dst = o;
    }
}

// ---------------------------------------------------------------------------
// bf16 GEMM: C[M,N] = A[M,K] @ Bw[N,K]^T (+bias).  128x128 block tile,
// 4 waves 2x2, each wave 64x64 via 4x4 mfma_f32_16x16x32_bf16.
// R6 structure (2-stage LDS, dist-2 prefetch, vmcnt(4), 2 barriers, XOR
// swizzle, XCD M-striping, launch_bounds(256,3)) with the K-loop
// STRENGTH-REDUCED (R6 post-mortem: VALUBusy 54% = addressing overhead):
//  - unroll x2 -> stage is compile-time; LDS DMA dests are constants
//  - frag reads: per-stage base pointer + i*1024B immediate offsets
//    (swizzle field is invariant under +16-row steps, so one base/stage)
//  - global srcs: 4 mutable pointers += 32 elems/ktile (no recompute)
//  - no tail clamp: always issue; <=128B over-read stays inside ws
// MODE: 0 bf16 store, 1 softplus rowsum, 2 fp32 + resid.
// ---------------------------------------------------------------------------
template<int MODE, int TM, int TN>
__launch_bounds__(256, 3)
__global__ void gemm_bt(const __hip_bfloat16* __restrict__ A,
                        const __hip_bfloat16* __restrict__ Bw,
                        const float* __restrict__ bias,
                        int M, int N, int K,
                        __hip_bfloat16* __restrict__ outb,
                        float* __restrict__ rowsum,
                        const float* __restrict__ resid,
                        float* __restrict__ outf) {
    constexpr int BM = 32 * TM, BN = 32 * TN;             // 128 x 128
    constexpr int ABUF = BM * 32, BBUF = BN * 32;         // elements/stage

    __shared__ __align__(16) __hip_bfloat16 sA[2 * ABUF]; // 16 KB
    __shared__ __align__(16) __hip_bfloat16 sB[2 * BBUF]; // 16 KB

    const int tid  = threadIdx.x;
    const int wave = tid >> 6, lane = tid & 63;
    const int wm = wave >> 1, wn = wave & 1;
    const int q = lane >> 4, lr = lane & 15;

    // XCD-aware remap (R6-proven: FETCH 140->52 GB): each XCD owns a
    // contiguous M-stripe; M varies fastest within the stripe.
    const int gx = gridDim.x, gy = gridDim.y;
    const int flat = blockIdx.y * gx + blockIdx.x;
    const int stripe = gy >> 3;
    const int xcd = flat & 7, local = flat >> 3;
    const int mt = xcd * stripe + (local % stripe);
    const int nt = local / stripe;
    const int m0 = mt * BM, n0 = nt * BN;

    floatx4 acc[TM][TN];
#pragma unroll
    for (int i = 0; i < TM; ++i)
#pragma unroll
        for (int j = 0; j < TN; ++j) acc[i][j] = (floatx4){0.f, 0.f, 0.f, 0.f};

    // staging map: chunk c = slot*256 + tid -> (row=c>>2, lds_slot=c&3);
    // fetch global chunk lds_slot^((row>>1)&3) so swizzled slot holds it.
    const int cA0 = tid,       rA0 = cA0 >> 2, sA0c = cA0 & 3;
    const int cA1 = 256 + tid, rA1 = cA1 >> 2, sA1c = cA1 & 3;
    const __hip_bfloat16* pa0 = A + (size_t)(m0 + rA0) * K + ((sA0c ^ ((rA0 >> 1) & 3)) << 3);
    const __hip_bfloat16* pa1 = A + (size_t)(m0 + rA1) * K + ((sA1c ^ ((rA1 >> 1) & 3)) << 3);
    const __hip_bfloat16* pb0 = Bw + (size_t)(n0 + rA0) * K + ((sA0c ^ ((rA0 >> 1) & 3)) << 3);
    const __hip_bfloat16* pb1 = Bw + (size_t)(n0 + rA1) * K + ((sA1c ^ ((rA1 >> 1) & 3)) << 3);

    // fragment base pointers, one per matrix per stage; frag i at +i*512 elems
    // (i*16 rows).  Swizzle field identical for all i (8i = 0 mod 4).
    const int r0a = wm * (TM * 16) + lr;
    const int r0b = wn * (TN * 16) + lr;
    const __hip_bfloat16* fA0 = &sA[r0a * 32 + ((q ^ ((r0a >> 1) & 3)) << 3)];
    const __hip_bfloat16* fA1 = fA0 + ABUF;
    const __hip_bfloat16* fB0 = &sB[r0b * 32 + ((q ^ ((r0b >> 1) & 3)) << 3)];
    const __hip_bfloat16* fB1 = fB0 + BBUF;

#define ISSUE(ST) do {                                                         \
        async_ld16(pa0, &sA[(ST) * ABUF + (0 * 256 + wave * 64) * 8]);         \
        async_ld16(pa1, &sA[(ST) * ABUF + (1 * 256 + wave * 64) * 8]);         \
        async_ld16(pb0, &sB[(ST) * BBUF + (0 * 256 + wave * 64) * 8]);         \
        async_ld16(pb1, &sB[(ST) * BBUF + (1 * 256 + wave * 64) * 8]);         \
        pa0 += 32; pa1 += 32; pb0 += 32; pb1 += 32;                            \
    } while (0)

#define HALF(ST, FA, FB) do {                                                  \
        asm volatile("" ::: "memory");                                         \
        __builtin_amdgcn_s_waitcnt(WAIT_VM(4));   /* this tile landed */       \
        __builtin_amdgcn_s_barrier();                                          \
        asm volatile("" ::: "memory");                                         \
        short8 af[TM], bfv[TN];                                                \
        _Pragma("unroll")                                                      \
        for (int i = 0; i < TM; ++i) af[i]  = *(const short8*)(FA + i * 512);  \
        _Pragma("unroll")                                                      \
        for (int j = 0; j < TN; ++j) bfv[j] = *(const short8*)(FB + j * 512);  \
        asm volatile("" ::: "memory");                                         \
        __builtin_amdgcn_s_waitcnt(WAIT_LGKM(0)); /* frags landed */           \
        __builtin_amdgcn_s_barrier();             /* stage reusable */         \
        asm volatile("" ::: "memory");                                         \
        ISSUE(ST);                                /* tile kt+2 -> stage ST */  \
        _Pragma("unroll")                                                      \
        for (int i = 0; i < TM; ++i)                                           \
            _Pragma("unroll")                                                  \
            for (int j = 0; j < TN; ++j)                                       \
                acc[i][j] = __builtin_amdgcn_mfma_f32_16x16x32_bf16(           \
                    af[i], bfv[j], acc[i][j], 0, 0, 0);                        \
    } while (0)

    const int nit = K >> 6;        // K/64: unrolled iterations (K mult of 64)
    ISSUE(0);                      // tile 0 -> stage 0
    ISSUE(1);                      // tile 1 -> stage 1
    for (int it = 0; it < nit; ++it) {
        HALF(0, fA0, fB0);
        HALF(1, fA1, fB1);
    }
#undef HALF
#undef ISSUE
    asm volatile("" ::: "memory");
    __builtin_amdgcn_s_waitcnt(WAIT_VM(0));       // drain 2 garbage tail tiles

    // epilogue: C/D layout col = lane&15, row = (lane>>4)*4 + reg
    if (MODE == 0) {
#pragma unroll
        for (int i = 0; i < TM; ++i) {
            const int row = m0 + wm * TM * 16 + i * 16 + q * 4;
#pragma unroll
            for (int j = 0; j < TN; ++j) {
                const int col = n0 + wn * TN * 16 + j * 16 + lr;
                const float bc = bias[col];
#pragma unroll
                for (int r = 0; r < 4; ++r)
                    outb[(size_t)(row + r) * N + col] = __float2bfloat16(acc[i][j][r] + bc);
            }
        }
    } else if (MODE == 1) {
#pragma unroll
        for (int i = 0; i < TM; ++i) {
            float rs[4] = {0.f, 0.f, 0.f, 0.f};
#pragma unroll
            for (int j = 0; j < TN; ++j) {
                const int col = n0 + wn * TN * 16 + j * 16 + lr;
                const float bc = bias[col];
#pragma unroll
                for (int r = 0; r < 4; ++r) {
                    float v = acc[i][j][r] + bc;
                    float sp = (v > 20.f) ? v : log1pf(expf(v));
                    rs[r] += sp;
                }
            }
#pragma unroll
            for (int r = 0; r < 4; ++r) {
                float v = rs[r];
                v += __shfl_xor(v, 1); v += __shfl_xor(v, 2);
                v += __shfl_xor(v, 4); v += __shfl_xor(v, 8);
                if (lr == 0)
                    atomicAdd(&rowsum[m0 + wm * TM * 16 + i * 16 + q * 4 + r], v);
            }
        }
    } else {
#pragma unroll
        for (int i = 0; i < TM; ++i) {
            const int row = m0 + wm * TM * 16 + i * 16 + q * 4;
#pragma unroll
            for (int j = 0; j < TN; ++j) {
                const int col = n0 + wn * TN * 16 + j * 16 + lr;
                const float bc = bias[col];
#pragma unroll
                for (int r = 0; r < 4; ++r) {
                    const size_t idx = (size_t)(row + r) * N + col;
                    outf[idx] = acc[i][j][r] + bc + resid[idx];
                }
            }
        }
    }
}

// ---------------------------------------------------------------------------
// depthwise conv (k=3, pad 1, along T) + bias + SiLU, 8 channels per thread.
// ---------------------------------------------------------------------------
__global__ void conv_silu_k(const __hip_bfloat16* __restrict__ xp,
                            const float* __restrict__ cw,
                            const float* __restrict__ cb,
                            __hip_bfloat16* __restrict__ xc) {
    const int idx8 = blockIdx.x * blockDim.x + threadIdx.x;
    const int e = (idx8 & (Esz / 8 - 1)) * 8;
    const int r = idx8 >> 8;
    const int t = r & (Tsz - 1);
    const unsigned short* row0 = (const unsigned short*)(xp + (size_t)r * (2 * Esz) + e);
    short8 vm1 = (t > 0)       ? *(const short8*)(row0 - 2 * Esz) : (short8){0,0,0,0,0,0,0,0};
    short8 v00 = *(const short8*)row0;
    short8 vp1 = (t < Tsz - 1) ? *(const short8*)(row0 + 2 * Esz) : (short8){0,0,0,0,0,0,0,0};
    short8 o;
#pragma unroll
    for (int k = 0; k < 8; ++k) {
        const int ek = e + k;
        float v = bf2f((unsigned short)vm1[k]) * cw[ek * 3 + 0]
                + bf2f((unsigned short)v00[k]) * cw[ek * 3 + 1]
                + bf2f((unsigned short)vp1[k]) * cw[ek * 3 + 2] + cb[ek];
        __hip_bfloat16 h = __float2bfloat16(v * sigmoidf_(v));
        o[k] = *(short*)&h;
    }
    *(short8*)(xc + (size_t)idx8 * 8) = o;
}

// ---------------------------------------------------------------------------
// pack B_w/C_w/D_w (each [16,2048] fp32) into Wb [48,2048] bf16
// ---------------------------------------------------------------------------
__global__ void pack_bcd(const float* __restrict__ Bw, const float* __restrict__ Cw,
                         const float* __restrict__ Dw, __hip_bfloat16* __restrict__ Wb) {
    const int idx = blockIdx.x * blockDim.x + threadIdx.x;
    if (idx >= 48 * Esz) return;
    const int row = idx >> 11, col = idx & (Esz - 1);
    float v;
    if (row < 16)      v = Bw[row * Esz + col];
    else if (row < 32) v = Cw[(row - 16) * Esz + col];
    else               v = Dw[(row - 32) * Esz + col];
    Wb[idx] = __float2bfloat16(v);
}

// ---------------------------------------------------------------------------
// B/C/D projections via MFMA skinny GEMM: xc[M,E] @ Wb[48,E]^T.
// ---------------------------------------------------------------------------
__launch_bounds__(256)
__global__ void bcd_mfma(const __hip_bfloat16* __restrict__ xc,
                         const __hip_bfloat16* __restrict__ Wb,
                         const float* __restrict__ Bb, const float* __restrict__ Cb,
                         const float* __restrict__ Db,
                         float* __restrict__ u, float* __restrict__ Ct) {
    __shared__ __align__(16) __hip_bfloat16 sA[64 * 32];
    __shared__ __align__(16) __hip_bfloat16 sW[48 * 32];
    const int tid = threadIdx.x;
    const int wave = tid >> 6, lane = tid & 63;
    const int q = lane >> 4, lr = lane & 15;
    const int m0 = blockIdx.x * 64;

    floatx4 acc[3];
#pragma unroll
    for (int j = 0; j < 3; ++j) acc[j] = (floatx4){0.f, 0.f, 0.f, 0.f};

    const int ra = wave * 16 + (lane >> 2);
    const int ca = (lane & 3) * 8;

    for (int kt = 0; kt < (Esz >> 5); ++kt) {
        const int k0 = kt << 5;
        __syncthreads();
        async_ld16(&xc[(size_t)(m0 + ra) * Esz + k0 + ca], &sA[wave * 512]);
        if (wave < 3)
            async_ld16(&Wb[(size_t)ra * Esz + k0 + ca], &sW[wave * 512]);
        __syncthreads();

        short8 af = *(const short8*)&sA[(wave * 16 + lr) * 32 + q * 8];
#pragma unroll
        for (int j = 0; j < 3; ++j) {
            short8 wf = *(const short8*)&sW[(j * 16 + lr) * 32 + q * 8];
            acc[j] = __builtin_amdgcn_mfma_f32_16x16x32_bf16(af, wf, acc[j], 0, 0, 0);
        }
    }

    const int row = m0 + wave * 16 + q * 4;
    const float bb = Bb[lr], cbv = Cb[lr], db = Db[lr];
#pragma unroll
    for (int r = 0; r < 4; ++r) {
        const float bt = acc[0][r] + bb;
        const float ct = acc[1][r] + cbv;
        const float dt = acc[2][r] + db;
        u [(size_t)(row + r) * Ssz + lr] = bt * dt;
        Ct[(size_t)(row + r) * Ssz + lr] = ct;
    }
}

// ---------------------------------------------------------------------------
// Sequential SSM scan (decay computed inline from rowsum).  One block/batch.
// ---------------------------------------------------------------------------
__global__ void scan_k(const float* __restrict__ rowsum, const float* __restrict__ u,
                       const float* __restrict__ Ct, float* __restrict__ ys) {
    const int b = blockIdx.x;
    const int tid = threadIdx.x;
    const int lane = tid & 63, wave = tid >> 6;
    __shared__ __align__(16) float su[256 * Ssz];
    __shared__ __align__(16) float sc[256 * Ssz];
    __shared__ float sp[256 * 17];
    __shared__ float sd[256];
    float st = 0.f;
    for (int t0 = 0; t0 < Tsz; t0 += 256) {
        __syncthreads();
        const float4* ub = (const float4*)(u  + ((size_t)b * Tsz + t0) * Ssz);
        const float4* cb = (const float4*)(Ct + ((size_t)b * Tsz + t0) * Ssz);
#pragma unroll
        for (int i = 0; i < 4; ++i) {
            ((float4*)su)[tid + i * 256] = ub[tid + i * 256];
            ((float4*)sc)[tid + i * 256] = cb[tid + i * 256];
        }
        {
            const float m = rowsum[b * Tsz + t0 + tid] * (1.f / (float)Esz);
            sd[tid] = expf(fminf(fmaxf(-m, -10.f), 10.f));
        }
        __syncthreads();
        if (wave == 0 && lane < 16) {
#pragma unroll 8
            for (int i = 0; i < 256; ++i) {
                st = st * sd[i] + su[i * Ssz + lane];
                sp[i * 17 + lane] = sc[i * Ssz + lane] * st;
            }
        }
        __syncthreads();
        float s = 0.f;
#pragma unroll
        for (int j = 0; j < 16; ++j) s += sp[tid * 17 + j];
        ys[b * Tsz + t0 + tid] = s;
    }
}

// ---------------------------------------------------------------------------
// y[r,e] = ys[r] * silu(x_gate[r,e]), 8 per thread; gate = xp cols [E,2E).
// ---------------------------------------------------------------------------
__global__ void ygate_k(const float* __restrict__ ys, const __hip_bfloat16* __restrict__ xp,
                        __hip_bfloat16* __restrict__ y) {
    const int idx8 = blockIdx.x * blockDim.x + threadIdx.x;
    const int e = (idx8 & (Esz / 8 - 1)) * 8;
    const int r = idx8 >> 8;
    const float yr = ys[r];
    short8 g = *(const short8*)(xp + (size_t)r * (2 * Esz) + Esz + e);
    short8 o;
#pragma unroll
    for (int k = 0; k < 8; ++k) {
        const float gv = bf2f((unsigned short)g[k]);
        __hip_bfloat16 h = __float2bfloat16(yr * gv * sigmoidf_(gv));
        o[k] = *(short*)&h;
    }
    *(short8*)(y + (size_t)idx8 * 8) = o;
}

// ---------------------------------------------------------------------------
extern "C" void kernel_launch(void* const* d_in, const int* in_sizes, int n_in,
                              void* d_out, int out_size, void* d_ws, size_t ws_size,
                              hipStream_t stream) {
    const float* x      = (const float*)d_in[0];
    const float* in_w   = (const float*)d_in[1];
    const float* in_b   = (const float*)d_in[2];
    const float* conv_w = (const float*)d_in[3];
    const float* conv_b = (const float*)d_in[4];
    const float* dt_w   = (const float*)d_in[5];
    const float* dt_b   = (const float*)d_in[6];
    const float* B_w    = (const float*)d_in[7];
    const float* B_b    = (const float*)d_in[8];
    const float* C_w    = (const float*)d_in[9];
    const float* C_b    = (const float*)d_in[10];
    const float* D_w    = (const float*)d_in[11];
    const float* D_b    = (const float*)d_in[12];
    const float* out_w  = (const float*)d_in[13];
    const float* out_b  = (const float*)d_in[14];
    float* out = (float*)d_out;

    char* ws = (char*)d_ws;
    auto alloc = [&](size_t bytes) {
        char* p = ws;
        ws += (bytes + 255) & ~(size_t)255;
        return p;
    };
    __hip_bfloat16* x_bf    = (__hip_bfloat16*)alloc((size_t)Mrows * Dsz * 2);
    __hip_bfloat16* inw_bf  = (__hip_bfloat16*)alloc((size_t)2 * Esz * Dsz * 2);
    __hip_bfloat16* dtw_bf  = (__hip_bfloat16*)alloc((size_t)Esz * Esz * 2);
    __hip_bfloat16* outw_bf = (__hip_bfloat16*)alloc((size_t)Dsz * Esz * 2);
    __hip_bfloat16* xp_bf   = (__hip_bfloat16*)alloc((size_t)Mrows * 2 * Esz * 2);
    __hip_bfloat16* xc_bf   = (__hip_bfloat16*)alloc((size_t)Mrows * Esz * 2);
    __hip_bfloat16* wb_bf   = (__hip_bfloat16*)alloc((size_t)48 * Esz * 2);
    float* rowsum = (float*)alloc(Mrows * 4);
    float* u_buf  = (float*)alloc((size_t)Mrows * Ssz * 4);
    float* ct_buf = (float*)alloc((size_t)Mrows * Ssz * 4);
    float* ys_buf = (float*)alloc(Mrows * 4);
    __hip_bfloat16* y_bf = xc_bf;   // reuse: xc dead after bcd/gemm<1>

    hipMemsetAsync(rowsum, 0, Mrows * 4, stream);

    // conversions (single merged kernel)
    cvt_all<<<4608, 256, 0, stream>>>((const float4*)x, (const float4*)in_w,
                                      (const float4*)dt_w, (const float4*)out_w,
                                      (ushort4*)x_bf, (ushort4*)inw_bf,
                                      (ushort4*)dtw_bf, (ushort4*)outw_bf);
    pack_bcd<<<48 * Esz / 256, 256, 0, stream>>>(B_w, C_w, D_w, wb_bf);

    // GEMM1: xp = x @ in_w^T + in_b  (M=8192, N=4096, K=1024) -> bf16
    gemm_bt<0, 4, 4><<<dim3(4096 / 128, Mrows / 128), 256, 0, stream>>>(
        x_bf, inw_bf, in_b, Mrows, 4096, 1024, xp_bf, nullptr, nullptr, nullptr);

    // conv + SiLU -> xc
    conv_silu_k<<<(Mrows * Esz / 8) / 256, 256, 0, stream>>>(xp_bf, conv_w, conv_b, xc_bf);

    // GEMM2: softplus(xc @ dt_w^T + dt_b) row-sums (M=8192, N=2048, K=2048)
    gemm_bt<1, 4, 4><<<dim3(Esz / 128, Mrows / 128), 256, 0, stream>>>(
        xc_bf, dtw_bf, dt_b, Mrows, Esz, Esz, nullptr, rowsum, nullptr, nullptr);

    // B/C/D projections + u = Bt*Dt
    bcd_mfma<<<Mrows / 64, 256, 0, stream>>>(xc_bf, wb_bf, B_b, C_b, D_b, u_buf, ct_buf);

    // sequential scan (decay inline) -> ys
    scan_k<<<Bsz, 256, 0, stream>>>(rowsum, u_buf, ct_buf, ys_buf);

    // y = ys * silu(x_gate) -> bf16 (into xc buffer)
    ygate_k<<<(Mrows * Esz / 8) / 256, 256, 0, stream>>>(ys_buf, xp_bf, y_bf);

    // GEMM3: out = x + y @ out_w^T + out_b  (M=8192, N=1024, K=2048) -> fp32
    gemm_bt<2, 4, 4><<<dim3(Dsz / 128, Mrows / 128), 256, 0, stream>>>(
        y_bf, outw_bf, out_b, Mrows, Dsz, Esz, nullptr, nullptr, x, out);
}

// Round 8
// 496.438 us; speedup vs baseline: 1.2448x; 1.0358x over previous
//
#include <hip/hip_runtime.h>
#include <hip/hip_bf16.h>

// Problem constants
#define Bsz 4
#define Tsz 2048
#define Dsz 1024
#define Ssz 16
#define Esz 2048
#define Mrows (Bsz*Tsz)        // 8192

typedef __attribute__((ext_vector_type(8))) short short8;
typedef __attribute__((ext_vector_type(4))) float floatx4;
typedef __attribute__((ext_vector_type(8))) int int8v;
typedef __attribute__((ext_vector_type(4))) int int4v;

__device__ __forceinline__ void async_ld16(const void* g, void* l) {
    __builtin_amdgcn_global_load_lds(
        (const __attribute__((address_space(1))) void*)g,
        (__attribute__((address_space(3))) void*)l,
        16, 0, 0);
}

__device__ __forceinline__ float sigmoidf_(float v) { return 1.f / (1.f + expf(-v)); }
__device__ __forceinline__ float bf2f(unsigned short u) {
    union { unsigned u32; float f; } c; c.u32 = (unsigned)u << 16; return c.f;
}
// pack 4 floats (pre-scaled) into 4 fp8 e4m3 bytes (HW saturating convert)
__device__ __forceinline__ int pk_fp8x4(float a, float b, float c, float d) {
    int lo = __builtin_amdgcn_cvt_pk_fp8_f32(a, b, 0, 0);
    int hi = __builtin_amdgcn_cvt_pk_fp8_f32(c, d, 0, 0);
    return (lo & 0xFFFF) | (hi << 16);
}

// s_waitcnt immediates (gfx9 encoding): vm[3:0]|exp[6:4]|lgkm[11:8]|vm[15:14]
#define WAIT_VM(N)   (0xF70 | (N))          // vmcnt(N), lgkm/exp no-wait
#define WAIT_LGKM(N) (0xC07F | ((N) << 8))  // lgkmcnt(N), vm/exp no-wait

// ---------------------------------------------------------------------------
// merged conversions: x -> fp8 (x1), in_w -> fp8 (x64), dt_w -> fp8 (x64),
// out_w -> bf16.  Scales lift the 0.02-sd weights out of e4m3 subnormals;
// the matching 2^-6 / 2^-4 unscale rides free in the MFMA scale operand.
// ---------------------------------------------------------------------------
#define CV_S0 2097152   // x:     8388608 f32 / 4
#define CV_S1 3145728   // in_w: +4194304 / 4
#define CV_S2 4194304   // dt_w: +4194304 / 4
#define CV_S3 4718592   // out_w:+2097152 / 4
__global__ void cvt_all(const float4* __restrict__ x,  const float4* __restrict__ iw,
                        const float4* __restrict__ dw, const float4* __restrict__ ow,
                        int* __restrict__ x8, int* __restrict__ iw8,
                        int* __restrict__ dw8, ushort4* __restrict__ owb) {
    int i = blockIdx.x * blockDim.x + threadIdx.x;
    const int stride = gridDim.x * blockDim.x;
    for (; i < CV_S3; i += stride) {
        if (i < CV_S0) {
            float4 v = x[i];
            x8[i] = pk_fp8x4(v.x, v.y, v.z, v.w);
        } else if (i < CV_S1) {
            const int j = i - CV_S0;
            float4 v = iw[j];
            iw8[j] = pk_fp8x4(v.x * 64.f, v.y * 64.f, v.z * 64.f, v.w * 64.f);
        } else if (i < CV_S2) {
            const int j = i - CV_S1;
            float4 v = dw[j];
            dw8[j] = pk_fp8x4(v.x * 64.f, v.y * 64.f, v.z * 64.f, v.w * 64.f);
        } else {
            const int j = i - CV_S2;
            float4 v = ow[j];
            __hip_bfloat16 a = __float2bfloat16(v.x), b = __float2bfloat16(v.y);
            __hip_bfloat16 c = __float2bfloat16(v.z), d = __float2bfloat16(v.w);
            ushort4 o;
            o.x = *(unsigned short*)&a; o.y = *(unsigned short*)&b;
            o.z = *(unsigned short*)&c; o.w = *(unsigned short*)&d;
            owb[j] = o;
        }
    }
}

// ---------------------------------------------------------------------------
// MX-fp8 GEMM: C[M,N] = (A*2^(SA-127)) @ (Bw*2^(SB-127))^T (+bias).
// A[M,K], Bw[N,K] in fp8 e4m3 bytes.  128x128 block tile, BK=128 bytes,
// 4 waves 2x2, each wave 64x64 via 4x4 mfma_scale_f32_16x16x128_f8f6f4
// (uniform E8M0 scale operands; K/128 k-tiles -> 4x fewer barriers/MFMAs
// than the bf16 path).  2-stage LDS (2x32 KB), dist-2 DMA prefetch,
// vmcnt(8) in-loop.  Mod-8 XOR chunk swizzle: frag ds_read_b128s are
// 2-way bank-aliased (free).  MODE: 0 bf16 store, 1 softplus rowsum.
// ---------------------------------------------------------------------------
template<int MODE, int SA, int SB>
__launch_bounds__(256, 2)
__global__ void gemm_fp8(const unsigned char* __restrict__ A,
                         const unsigned char* __restrict__ Bw,
                         const float* __restrict__ bias,
                         int M, int N, int K,
                         __hip_bfloat16* __restrict__ outb,
                         float* __restrict__ rowsum) {
    __shared__ __align__(16) unsigned char sA[2 * 16384];
    __shared__ __align__(16) unsigned char sB[2 * 16384];

    const int tid  = threadIdx.x;
    const int wave = tid >> 6, lane = tid & 63;
    const int wm = wave >> 1, wn = wave & 1;
    const int q = lane >> 4, lr = lane & 15;

    // XCD-aware remap (R6-proven): each XCD owns a contiguous M-stripe.
    const int gx = gridDim.x, gy = gridDim.y;
    const int flat = blockIdx.y * gx + blockIdx.x;
    const int stripe = gy >> 3;
    const int xcd = flat & 7, local = flat >> 3;
    const int mt = xcd * stripe + (local % stripe);
    const int nt = local / stripe;
    const int m0 = mt * 128, n0 = nt * 128;

    floatx4 acc[4][4];
#pragma unroll
    for (int i = 0; i < 4; ++i)
#pragma unroll
        for (int j = 0; j < 4; ++j) acc[i][j] = (floatx4){0.f, 0.f, 0.f, 0.f};

    // staging: tile = 128 rows x 8 chunks(16B); slot_idx = i*256 + tid;
    // LDS slot s of row r holds global chunk s^(r&7).
    const unsigned char* pa[4];
    const unsigned char* pb[4];
#pragma unroll
    for (int i = 0; i < 4; ++i) {
        const int idx = i * 256 + tid, row = idx >> 3, s = idx & 7;
        const int g = (s ^ (row & 7)) * 16;
        pa[i] = A  + (size_t)(m0 + row) * K + g;
        pb[i] = Bw + (size_t)(n0 + row) * K + g;
    }

    // fragment LDS byte offsets (frag i at +i*2048; (r+16i)&7 == r&7)
    const int rA = wm * 64 + lr, rB = wn * 64 + lr;
    const int oA0 = rA * 128 + (((2 * q)     ^ (rA & 7)) * 16);
    const int oA1 = rA * 128 + (((2 * q + 1) ^ (rA & 7)) * 16);
    const int oB0 = rB * 128 + (((2 * q)     ^ (rB & 7)) * 16);
    const int oB1 = rB * 128 + (((2 * q + 1) ^ (rB & 7)) * 16);

#define F8_ISSUE(ST) do {                                                      \
        _Pragma("unroll")                                                      \
        for (int i = 0; i < 4; ++i) {                                          \
            async_ld16(pa[i], &sA[(ST) * 16384 + (i * 256 + wave * 64) * 16]); \
            pa[i] += 128;                                                      \
        }                                                                      \
        _Pragma("unroll")                                                      \
        for (int i = 0; i < 4; ++i) {                                          \
            async_ld16(pb[i], &sB[(ST) * 16384 + (i * 256 + wave * 64) * 16]); \
            pb[i] += 128;                                                      \
        }                                                                      \
    } while (0)

#define F8_STEP(ST) do {                                                       \
        asm volatile("" ::: "memory");                                         \
        __builtin_amdgcn_s_waitcnt(WAIT_VM(8));   /* this tile landed */       \
        __builtin_amdgcn_s_barrier();                                          \
        asm volatile("" ::: "memory");                                         \
        int8v a8[4], b8[4];                                                    \
        _Pragma("unroll")                                                      \
        for (int i = 0; i < 4; ++i) {                                          \
            int4v lo = *(const int4v*)&sA[(ST) * 16384 + oA0 + i * 2048];      \
            int4v hi = *(const int4v*)&sA[(ST) * 16384 + oA1 + i * 2048];      \
            a8[i] = __builtin_shufflevector(lo, hi, 0, 1, 2, 3, 4, 5, 6, 7);   \
        }                                                                      \
        _Pragma("unroll")                                                      \
        for (int j = 0; j < 4; ++j) {                                          \
            int4v lo = *(const int4v*)&sB[(ST) * 16384 + oB0 + j * 2048];      \
            int4v hi = *(const int4v*)&sB[(ST) * 16384 + oB1 + j * 2048];      \
            b8[j] = __builtin_shufflevector(lo, hi, 0, 1, 2, 3, 4, 5, 6, 7);   \
        }                                                                      \
        asm volatile("" ::: "memory");                                         \
        __builtin_amdgcn_s_waitcnt(WAIT_LGKM(0)); /* frags landed */           \
        __builtin_amdgcn_s_barrier();             /* stage reusable */         \
        asm volatile("" ::: "memory");                                         \
        F8_ISSUE(ST);                             /* tile kt+2 -> stage ST */  \
        _Pragma("unroll")                                                      \
        for (int i = 0; i < 4; ++i)                                            \
            _Pragma("unroll")                                                  \
            for (int j = 0; j < 4; ++j)                                        \
                acc[i][j] = __builtin_amdgcn_mfma_scale_f32_16x16x128_f8f6f4(  \
                    a8[i], b8[j], acc[i][j], 0, 0, 0, SA, 0, SB);              \
    } while (0)

    const int nit = K >> 8;        // (K/128)/2 double-steps; K mult of 256
    F8_ISSUE(0);                   // tile 0 -> stage 0
    F8_ISSUE(1);                   // tile 1 -> stage 1
    for (int it = 0; it < nit; ++it) {
        F8_STEP(0);
        F8_STEP(1);
    }
#undef F8_STEP
#undef F8_ISSUE
    asm volatile("" ::: "memory");
    __builtin_amdgcn_s_waitcnt(WAIT_VM(0));       // drain 2 garbage tail tiles

    // epilogue: C/D layout col = lane&15, row = (lane>>4)*4 + reg
    if (MODE == 0) {
#pragma unroll
        for (int i = 0; i < 4; ++i) {
            const int row = m0 + wm * 64 + i * 16 + q * 4;
#pragma unroll
            for (int j = 0; j < 4; ++j) {
                const int col = n0 + wn * 64 + j * 16 + lr;
                const float bc = bias[col];
#pragma unroll
                for (int r = 0; r < 4; ++r)
                    outb[(size_t)(row + r) * N + col] = __float2bfloat16(acc[i][j][r] + bc);
            }
        }
    } else {
#pragma unroll
        for (int i = 0; i < 4; ++i) {
            float rs[4] = {0.f, 0.f, 0.f, 0.f};
#pragma unroll
            for (int j = 0; j < 4; ++j) {
                const int col = n0 + wn * 64 + j * 16 + lr;
                const float bc = bias[col];
#pragma unroll
                for (int r = 0; r < 4; ++r) {
                    float v = acc[i][j][r] + bc;
                    float sp = (v > 20.f) ? v : log1pf(expf(v));
                    rs[r] += sp;
                }
            }
#pragma unroll
            for (int r = 0; r < 4; ++r) {
                float v = rs[r];
                v += __shfl_xor(v, 1); v += __shfl_xor(v, 2);
                v += __shfl_xor(v, 4); v += __shfl_xor(v, 8);
                if (lr == 0)
                    atomicAdd(&rowsum[m0 + wm * 64 + i * 16 + q * 4 + r], v);
            }
        }
    }
}

// ---------------------------------------------------------------------------
// bf16 GEMM (R7, unchanged): used for GEMM3 (output-side, keep bf16).
// ---------------------------------------------------------------------------
template<int MODE, int TM, int TN>
__launch_bounds__(256, 3)
__global__ void gemm_bt(const __hip_bfloat16* __restrict__ A,
                        const __hip_bfloat16* __restrict__ Bw,
                        const float* __restrict__ bias,
                        int M, int N, int K,
                        __hip_bfloat16* __restrict__ outb,
                        float* __restrict__ rowsum,
                        const float* __restrict__ resid,
                        float* __restrict__ outf) {
    constexpr int BM = 32 * TM, BN = 32 * TN;
    constexpr int ABUF = BM * 32, BBUF = BN * 32;

    __shared__ __align__(16) __hip_bfloat16 sA[2 * ABUF];
    __shared__ __align__(16) __hip_bfloat16 sB[2 * BBUF];

    const int tid  = threadIdx.x;
    const int wave = tid >> 6, lane = tid & 63;
    const int wm = wave >> 1, wn = wave & 1;
    const int q = lane >> 4, lr = lane & 15;

    const int gx = gridDim.x, gy = gridDim.y;
    const int flat = blockIdx.y * gx + blockIdx.x;
    const int stripe = gy >> 3;
    const int xcd = flat & 7, local = flat >> 3;
    const int mt = xcd * stripe + (local % stripe);
    const int nt = local / stripe;
    const int m0 = mt * BM, n0 = nt * BN;

    floatx4 acc[TM][TN];
#pragma unroll
    for (int i = 0; i < TM; ++i)
#pragma unroll
        for (int j = 0; j < TN; ++j) acc[i][j] = (floatx4){0.f, 0.f, 0.f, 0.f};

    const int cA0 = tid,       rA0 = cA0 >> 2, sA0c = cA0 & 3;
    const int cA1 = 256 + tid, rA1 = cA1 >> 2, sA1c = cA1 & 3;
    const __hip_bfloat16* pa0 = A + (size_t)(m0 + rA0) * K + ((sA0c ^ ((rA0 >> 1) & 3)) << 3);
    const __hip_bfloat16* pa1 = A + (size_t)(m0 + rA1) * K + ((sA1c ^ ((rA1 >> 1) & 3)) << 3);
    const __hip_bfloat16* pb0 = Bw + (size_t)(n0 + rA0) * K + ((sA0c ^ ((rA0 >> 1) & 3)) << 3);
    const __hip_bfloat16* pb1 = Bw + (size_t)(n0 + rA1) * K + ((sA1c ^ ((rA1 >> 1) & 3)) << 3);

    const int r0a = wm * (TM * 16) + lr;
    const int r0b = wn * (TN * 16) + lr;
    const __hip_bfloat16* fA0 = &sA[r0a * 32 + ((q ^ ((r0a >> 1) & 3)) << 3)];
    const __hip_bfloat16* fA1 = fA0 + ABUF;
    const __hip_bfloat16* fB0 = &sB[r0b * 32 + ((q ^ ((r0b >> 1) & 3)) << 3)];
    const __hip_bfloat16* fB1 = fB0 + BBUF;

#define ISSUE(ST) do {                                                         \
        async_ld16(pa0, &sA[(ST) * ABUF + (0 * 256 + wave * 64) * 8]);         \
        async_ld16(pa1, &sA[(ST) * ABUF + (1 * 256 + wave * 64) * 8]);         \
        async_ld16(pb0, &sB[(ST) * BBUF + (0 * 256 + wave * 64) * 8]);         \
        async_ld16(pb1, &sB[(ST) * BBUF + (1 * 256 + wave * 64) * 8]);         \
        pa0 += 32; pa1 += 32; pb0 += 32; pb1 += 32;                            \
    } while (0)

#define HALF(ST, FA, FB) do {                                                  \
        asm volatile("" ::: "memory");                                         \
        __builtin_amdgcn_s_waitcnt(WAIT_VM(4));                                \
        __builtin_amdgcn_s_barrier();                                          \
        asm volatile("" ::: "memory");                                         \
        short8 af[TM], bfv[TN];                                                \
        _Pragma("unroll")                                                      \
        for (int i = 0; i < TM; ++i) af[i]  = *(const short8*)(FA + i * 512);  \
        _Pragma("unroll")                                                      \
        for (int j = 0; j < TN; ++j) bfv[j] = *(const short8*)(FB + j * 512);  \
        asm volatile("" ::: "memory");                                         \
        __builtin_amdgcn_s_waitcnt(WAIT_LGKM(0));                              \
        __builtin_amdgcn_s_barrier();                                          \
        asm volatile("" ::: "memory");                                         \
        ISSUE(ST);                                                             \
        _Pragma("unroll")                                                      \
        for (int i = 0; i < TM; ++i)                                           \
            _Pragma("unroll")                                                  \
            for (int j = 0; j < TN; ++j)                                       \
                acc[i][j] = __builtin_amdgcn_mfma_f32_16x16x32_bf16(           \
                    af[i], bfv[j], acc[i][j], 0, 0, 0);                        \
    } while (0)

    const int nit = K >> 6;
    ISSUE(0);
    ISSUE(1);
    for (int it = 0; it < nit; ++it) {
        HALF(0, fA0, fB0);
        HALF(1, fA1, fB1);
    }
#undef HALF
#undef ISSUE
    asm volatile("" ::: "memory");
    __builtin_amdgcn_s_waitcnt(WAIT_VM(0));

    if (MODE == 0) {
#pragma unroll
        for (int i = 0; i < TM; ++i) {
            const int row = m0 + wm * TM * 16 + i * 16 + q * 4;
#pragma unroll
            for (int j = 0; j < TN; ++j) {
                const int col = n0 + wn * TN * 16 + j * 16 + lr;
                const float bc = bias[col];
#pragma unroll
                for (int r = 0; r < 4; ++r)
                    outb[(size_t)(row + r) * N + col] = __float2bfloat16(acc[i][j][r] + bc);
            }
        }
    } else if (MODE == 1) {
#pragma unroll
        for (int i = 0; i < TM; ++i) {
            float rs[4] = {0.f, 0.f, 0.f, 0.f};
#pragma unroll
            for (int j = 0; j < TN; ++j) {
                const int col = n0 + wn * TN * 16 + j * 16 + lr;
                const float bc = bias[col];
#pragma unroll
                for (int r = 0; r < 4; ++r) {
                    float v = acc[i][j][r] + bc;
                    float sp = (v > 20.f) ? v : log1pf(expf(v));
                    rs[r] += sp;
                }
            }
#pragma unroll
            for (int r = 0; r < 4; ++r) {
                float v = rs[r];
                v += __shfl_xor(v, 1); v += __shfl_xor(v, 2);
                v += __shfl_xor(v, 4); v += __shfl_xor(v, 8);
                if (lr == 0)
                    atomicAdd(&rowsum[m0 + wm * TM * 16 + i * 16 + q * 4 + r], v);
            }
        }
    } else {
#pragma unroll
        for (int i = 0; i < TM; ++i) {
            const int row = m0 + wm * TM * 16 + i * 16 + q * 4;
#pragma unroll
            for (int j = 0; j < TN; ++j) {
                const int col = n0 + wn * TN * 16 + j * 16 + lr;
                const float bc = bias[col];
#pragma unroll
                for (int r = 0; r < 4; ++r) {
                    const size_t idx = (size_t)(row + r) * N + col;
                    outf[idx] = acc[i][j][r] + bc + resid[idx];
                }
            }
        }
    }
}

// ---------------------------------------------------------------------------
// depthwise conv (k=3, pad 1, along T) + bias + SiLU, 8 channels/thread.
// Writes bf16 xc (for bcd_mfma) AND fp8 xc*16 (for GEMM2's MX-fp8 A).
// ---------------------------------------------------------------------------
__global__ void conv_silu_k(const __hip_bfloat16* __restrict__ xp,
                            const float* __restrict__ cw,
                            const float* __restrict__ cb,
                            __hip_bfloat16* __restrict__ xc,
                            int2* __restrict__ xc8) {
    const int idx8 = blockIdx.x * blockDim.x + threadIdx.x;
    const int e = (idx8 & (Esz / 8 - 1)) * 8;
    const int r = idx8 >> 8;
    const int t = r & (Tsz - 1);
    const unsigned short* row0 = (const unsigned short*)(xp + (size_t)r * (2 * Esz) + e);
    short8 vm1 = (t > 0)       ? *(const short8*)(row0 - 2 * Esz) : (short8){0,0,0,0,0,0,0,0};
    short8 v00 = *(const short8*)row0;
    short8 vp1 = (t < Tsz - 1) ? *(const short8*)(row0 + 2 * Esz) : (short8){0,0,0,0,0,0,0,0};
    short8 o;
    float sil[8];
#pragma unroll
    for (int k = 0; k < 8; ++k) {
        const int ek = e + k;
        float v = bf2f((unsigned short)vm1[k]) * cw[ek * 3 + 0]
                + bf2f((unsigned short)v00[k]) * cw[ek * 3 + 1]
                + bf2f((unsigned short)vp1[k]) * cw[ek * 3 + 2] + cb[ek];
        sil[k] = v * sigmoidf_(v);
        __hip_bfloat16 h = __float2bfloat16(sil[k]);
        o[k] = *(short*)&h;
    }
    *(short8*)(xc + (size_t)idx8 * 8) = o;
    int2 p;
    p.x = pk_fp8x4(sil[0] * 16.f, sil[1] * 16.f, sil[2] * 16.f, sil[3] * 16.f);
    p.y = pk_fp8x4(sil[4] * 16.f, sil[5] * 16.f, sil[6] * 16.f, sil[7] * 16.f);
    xc8[idx8] = p;
}

// ---------------------------------------------------------------------------
// pack B_w/C_w/D_w (each [16,2048] fp32) into Wb [48,2048] bf16
// ---------------------------------------------------------------------------
__global__ void pack_bcd(const float* __restrict__ Bw, const float* __restrict__ Cw,
                         const float* __restrict__ Dw, __hip_bfloat16* __restrict__ Wb) {
    const int idx = blockIdx.x * blockDim.x + threadIdx.x;
    if (idx >= 48 * Esz) return;
    const int row = idx >> 11, col = idx & (Esz - 1);
    float v;
    if (row < 16)      v = Bw[row * Esz + col];
    else if (row < 32) v = Cw[(row - 16) * Esz + col];
    else               v = Dw[(row - 32) * Esz + col];
    Wb[idx] = __float2bfloat16(v);
}

// ---------------------------------------------------------------------------
// B/C/D projections via MFMA skinny GEMM: xc[M,E] @ Wb[48,E]^T.
// ---------------------------------------------------------------------------
__launch_bounds__(256)
__global__ void bcd_mfma(const __hip_bfloat16* __restrict__ xc,
                         const __hip_bfloat16* __restrict__ Wb,
                         const float* __restrict__ Bb, const float* __restrict__ Cb,
                         const float* __restrict__ Db,
                         float* __restrict__ u, float* __restrict__ Ct) {
    __shared__ __align__(16) __hip_bfloat16 sA[64 * 32];
    __shared__ __align__(16) __hip_bfloat16 sW[48 * 32];
    const int tid = threadIdx.x;
    const int wave = tid >> 6, lane = tid & 63;
    const int q = lane >> 4, lr = lane & 15;
    const int m0 = blockIdx.x * 64;

    floatx4 acc[3];
#pragma unroll
    for (int j = 0; j < 3; ++j) acc[j] = (floatx4){0.f, 0.f, 0.f, 0.f};

    const int ra = wave * 16 + (lane >> 2);
    const int ca = (lane & 3) * 8;

    for (int kt = 0; kt < (Esz >> 5); ++kt) {
        const int k0 = kt << 5;
        __syncthreads();
        async_ld16(&xc[(size_t)(m0 + ra) * Esz + k0 + ca], &sA[wave * 512]);
        if (wave < 3)
            async_ld16(&Wb[(size_t)ra * Esz + k0 + ca], &sW[wave * 512]);
        __syncthreads();

        short8 af = *(const short8*)&sA[(wave * 16 + lr) * 32 + q * 8];
#pragma unroll
        for (int j = 0; j < 3; ++j) {
            short8 wf = *(const short8*)&sW[(j * 16 + lr) * 32 + q * 8];
            acc[j] = __builtin_amdgcn_mfma_f32_16x16x32_bf16(af, wf, acc[j], 0, 0, 0);
        }
    }

    const int row = m0 + wave * 16 + q * 4;
    const float bb = Bb[lr], cbv = Cb[lr], db = Db[lr];
#pragma unroll
    for (int r = 0; r < 4; ++r) {
        const float bt = acc[0][r] + bb;
        const float ct = acc[1][r] + cbv;
        const float dt = acc[2][r] + db;
        u [(size_t)(row + r) * Ssz + lr] = bt * dt;
        Ct[(size_t)(row + r) * Ssz + lr] = ct;
    }
}

// ---------------------------------------------------------------------------
// Sequential SSM scan (decay computed inline from rowsum).  One block/batch.
// ---------------------------------------------------------------------------
__global__ void scan_k(const float* __restrict__ rowsum, const float* __restrict__ u,
                       const float* __restrict__ Ct, float* __restrict__ ys) {
    const int b = blockIdx.x;
    const int tid = threadIdx.x;
    const int lane = tid & 63, wave = tid >> 6;
    __shared__ __align__(16) float su[256 * Ssz];
    __shared__ __align__(16) float sc[256 * Ssz];
    __shared__ float sp[256 * 17];
    __shared__ float sd[256];
    float st = 0.f;
    for (int t0 = 0; t0 < Tsz; t0 += 256) {
        __syncthreads();
        const float4* ub = (const float4*)(u  + ((size_t)b * Tsz + t0) * Ssz);
        const float4* cb = (const float4*)(Ct + ((size_t)b * Tsz + t0) * Ssz);
#pragma unroll
        for (int i = 0; i < 4; ++i) {
            ((float4*)su)[tid + i * 256] = ub[tid + i * 256];
            ((float4*)sc)[tid + i * 256] = cb[tid + i * 256];
        }
        {
            const float m = rowsum[b * Tsz + t0 + tid] * (1.f / (float)Esz);
            sd[tid] = expf(fminf(fmaxf(-m, -10.f), 10.f));
        }
        __syncthreads();
        if (wave == 0 && lane < 16) {
#pragma unroll 8
            for (int i = 0; i < 256; ++i) {
                st = st * sd[i] + su[i * Ssz + lane];
                sp[i * 17 + lane] = sc[i * Ssz + lane] * st;
            }
        }
        __syncthreads();
        float s = 0.f;
#pragma unroll
        for (int j = 0; j < 16; ++j) s += sp[tid * 17 + j];
        ys[b * Tsz + t0 + tid] = s;
    }
}

// ---------------------------------------------------------------------------
// y[r,e] = ys[r] * silu(x_gate[r,e]), 8 per thread; gate = xp cols [E,2E).
// ---------------------------------------------------------------------------
__global__ void ygate_k(const float* __restrict__ ys, const __hip_bfloat16* __restrict__ xp,
                        __hip_bfloat16* __restrict__ y) {
    const int idx8 = blockIdx.x * blockDim.x + threadIdx.x;
    const int e = (idx8 & (Esz / 8 - 1)) * 8;
    const int r = idx8 >> 8;
    const float yr = ys[r];
    short8 g = *(const short8*)(xp + (size_t)r * (2 * Esz) + Esz + e);
    short8 o;
#pragma unroll
    for (int k = 0; k < 8; ++k) {
        const float gv = bf2f((unsigned short)g[k]);
        __hip_bfloat16 h = __float2bfloat16(yr * gv * sigmoidf_(gv));
        o[k] = *(short*)&h;
    }
    *(short8*)(y + (size_t)idx8 * 8) = o;
}

// ---------------------------------------------------------------------------
extern "C" void kernel_launch(void* const* d_in, const int* in_sizes, int n_in,
                              void* d_out, int out_size, void* d_ws, size_t ws_size,
                              hipStream_t stream) {
    const float* x      = (const float*)d_in[0];
    const float* in_w   = (const float*)d_in[1];
    const float* in_b   = (const float*)d_in[2];
    const float* conv_w = (const float*)d_in[3];
    const float* conv_b = (const float*)d_in[4];
    const float* dt_w   = (const float*)d_in[5];
    const float* dt_b   = (const float*)d_in[6];
    const float* B_w    = (const float*)d_in[7];
    const float* B_b    = (const float*)d_in[8];
    const float* C_w    = (const float*)d_in[9];
    const float* C_b    = (const float*)d_in[10];
    const float* D_w    = (const float*)d_in[11];
    const float* D_b    = (const float*)d_in[12];
    const float* out_w  = (const float*)d_in[13];
    const float* out_b  = (const float*)d_in[14];
    float* out = (float*)d_out;

    char* ws = (char*)d_ws;
    auto alloc = [&](size_t bytes) {
        char* p = ws;
        ws += (bytes + 255) & ~(size_t)255;
        return p;
    };
    unsigned char* x_f8    = (unsigned char*)alloc((size_t)Mrows * Dsz);        //  8 MB
    unsigned char* inw_f8  = (unsigned char*)alloc((size_t)2 * Esz * Dsz);      //  4 MB
    unsigned char* dtw_f8  = (unsigned char*)alloc((size_t)Esz * Esz);          //  4 MB
    __hip_bfloat16* outw_bf = (__hip_bfloat16*)alloc((size_t)Dsz * Esz * 2);    //  4 MB
    __hip_bfloat16* xp_bf   = (__hip_bfloat16*)alloc((size_t)Mrows * 2 * Esz * 2); // 64 MB
    __hip_bfloat16* xc_bf   = (__hip_bfloat16*)alloc((size_t)Mrows * Esz * 2);  // 32 MB
    unsigned char* xc_f8    = (unsigned char*)alloc((size_t)Mrows * Esz);       // 16 MB
    __hip_bfloat16* wb_bf   = (__hip_bfloat16*)alloc((size_t)48 * Esz * 2);
    float* rowsum = (float*)alloc(Mrows * 4);
    float* u_buf  = (float*)alloc((size_t)Mrows * Ssz * 4);
    float* ct_buf = (float*)alloc((size_t)Mrows * Ssz * 4);
    float* ys_buf = (float*)alloc(Mrows * 4);
    (void)alloc(4096);              // pad: fp8 tail over-reads stay in ws
    __hip_bfloat16* y_bf = xc_bf;   // reuse: xc dead after bcd/gemm2

    hipMemsetAsync(rowsum, 0, Mrows * 4, stream);

    // conversions: x/in_w/dt_w -> fp8 (scaled), out_w -> bf16
    cvt_all<<<4608, 256, 0, stream>>>((const float4*)x, (const float4*)in_w,
                                      (const float4*)dt_w, (const float4*)out_w,
                                      (int*)x_f8, (int*)inw_f8, (int*)dtw_f8,
                                      (ushort4*)outw_bf);
    pack_bcd<<<48 * Esz / 256, 256, 0, stream>>>(B_w, C_w, D_w, wb_bf);

    // GEMM1 (MX-fp8): xp = x @ in_w^T + in_b  (8192x4096x1024) -> bf16
    // scales: A = x (2^0 -> 127), B = in_w*64 (2^-6 -> 121)
    gemm_fp8<0, 127, 121><<<dim3(4096 / 128, Mrows / 128), 256, 0, stream>>>(
        x_f8, inw_f8, in_b, Mrows, 4096, 1024, xp_bf, nullptr);

    // conv + SiLU -> xc (bf16) + xc*16 (fp8)
    conv_silu_k<<<(Mrows * Esz / 8) / 256, 256, 0, stream>>>(
        xp_bf, conv_w, conv_b, xc_bf, (int2*)xc_f8);

    // GEMM2 (MX-fp8): softplus(xc @ dt_w^T + dt_b) row-sums (8192x2048x2048)
    // scales: A = xc*16 (2^-4 -> 123), B = dt_w*64 (2^-6 -> 121)
    gemm_fp8<1, 123, 121><<<dim3(Esz / 128, Mrows / 128), 256, 0, stream>>>(
        xc_f8, dtw_f8, dt_b, Mrows, Esz, Esz, nullptr, rowsum);

    // B/C/D projections + u = Bt*Dt (bf16 xc)
    bcd_mfma<<<Mrows / 64, 256, 0, stream>>>(xc_bf, wb_bf, B_b, C_b, D_b, u_buf, ct_buf);

    // sequential scan (decay inline) -> ys
    scan_k<<<Bsz, 256, 0, stream>>>(rowsum, u_buf, ct_buf, ys_buf);

    // y = ys * silu(x_gate) -> bf16 (into xc buffer)
    ygate_k<<<(Mrows * Esz / 8) / 256, 256, 0, stream>>>(ys_buf, xp_bf, y_bf);

    // GEMM3 (bf16): out = x + y @ out_w^T + out_b  (8192x1024x2048) -> fp32
    gemm_bt<2, 4, 4><<<dim3(Dsz / 128, Mrows / 128), 256, 0, stream>>>(
        y_bf, outw_bf, out_b, Mrows, Dsz, Esz, nullptr, nullptr, x, out);
}

// Round 9
// 438.820 us; speedup vs baseline: 1.4082x; 1.1313x over previous
//
#include <hip/hip_runtime.h>
#include <hip/hip_bf16.h>

// Problem constants
#define Bsz 4
#define Tsz 2048
#define Dsz 1024
#define Ssz 16
#define Esz 2048
#define Mrows (Bsz*Tsz)        // 8192

typedef __attribute__((ext_vector_type(8))) short short8;
typedef __attribute__((ext_vector_type(4))) float floatx4;
typedef __attribute__((ext_vector_type(8))) int int8v;
typedef __attribute__((ext_vector_type(4))) int int4v;

__device__ __forceinline__ void async_ld16(const void* g, void* l) {
    __builtin_amdgcn_global_load_lds(
        (const __attribute__((address_space(1))) void*)g,
        (__attribute__((address_space(3))) void*)l,
        16, 0, 0);
}

__device__ __forceinline__ float sigmoidf_(float v) { return 1.f / (1.f + expf(-v)); }
__device__ __forceinline__ float bf2f(unsigned short u) {
    union { unsigned u32; float f; } c; c.u32 = (unsigned)u << 16; return c.f;
}
__device__ __forceinline__ int pk_fp8x4(float a, float b, float c, float d) {
    int lo = __builtin_amdgcn_cvt_pk_fp8_f32(a, b, 0, 0);
    int hi = __builtin_amdgcn_cvt_pk_fp8_f32(c, d, 0, 0);
    return (lo & 0xFFFF) | (hi << 16);
}

// s_waitcnt immediates (gfx9): vm[3:0]|exp[6:4]|lgkm[11:8]|vm[15:14]
#define WAIT_VM(N)   (0xF70 | (N))
#define WAIT_LGKM(N) (0xC07F | ((N) << 8))

// ---------------------------------------------------------------------------
// merged conversions: x -> fp8 (x1), in_w -> fp8 (x64), dt_w -> fp8 (x64),
// out_w -> fp8 (x64).  Scales lift 0.02-sd weights out of e4m3 subnormals;
// the matching unscale rides free in the MFMA scale operand.
// ---------------------------------------------------------------------------
#define CV_S0 2097152   // x:     8388608 f32 / 4
#define CV_S1 3145728   // in_w: +4194304 / 4
#define CV_S2 4194304   // dt_w: +4194304 / 4
#define CV_S3 4718592   // out_w:+2097152 / 4
__global__ void cvt_all(const float4* __restrict__ x,  const float4* __restrict__ iw,
                        const float4* __restrict__ dw, const float4* __restrict__ ow,
                        int* __restrict__ x8, int* __restrict__ iw8,
                        int* __restrict__ dw8, int* __restrict__ ow8) {
    int i = blockIdx.x * blockDim.x + threadIdx.x;
    const int stride = gridDim.x * blockDim.x;
    for (; i < CV_S3; i += stride) {
        if (i < CV_S0) {
            float4 v = x[i];
            x8[i] = pk_fp8x4(v.x, v.y, v.z, v.w);
        } else if (i < CV_S1) {
            const int j = i - CV_S0;
            float4 v = iw[j];
            iw8[j] = pk_fp8x4(v.x * 64.f, v.y * 64.f, v.z * 64.f, v.w * 64.f);
        } else if (i < CV_S2) {
            const int j = i - CV_S1;
            float4 v = dw[j];
            dw8[j] = pk_fp8x4(v.x * 64.f, v.y * 64.f, v.z * 64.f, v.w * 64.f);
        } else {
            const int j = i - CV_S2;
            float4 v = ow[j];
            ow8[j] = pk_fp8x4(v.x * 64.f, v.y * 64.f, v.z * 64.f, v.w * 64.f);
        }
    }
}

// ---------------------------------------------------------------------------
// MX-fp8 GEMM: C[M,N] = (A*2^(SA-127)) @ (Bw*2^(SB-127))^T (+bias).
// 128x64 block tile (R8 post-mortem: 64KB LDS -> 2 blk/CU was the drag;
// 48KB ring -> 3 blk/CU), BK=128B, 4 waves 2x2, each wave 64x32 via 4x2
// mfma_scale_f32_16x16x128_f8f6f4 (uniform E8M0 scales).  2-stage LDS,
// dist-2 DMA prefetch, vmcnt(6) in-loop, mod-8 XOR chunk swizzle.
// MODE: 0 bf16 store, 1 softplus rowsum, 2 fp32 resid + ys[row]*acc.
// ---------------------------------------------------------------------------
template<int MODE, int SA, int SB>
__launch_bounds__(256, 3)
__global__ void gemm_f8(const unsigned char* __restrict__ A,
                        const unsigned char* __restrict__ Bw,
                        const float* __restrict__ bias,
                        int M, int N, int K,
                        __hip_bfloat16* __restrict__ outb,
                        float* __restrict__ rowsum,
                        const float* __restrict__ resid,
                        const float* __restrict__ ysv,
                        float* __restrict__ outf) {
    __shared__ __align__(16) unsigned char sA[2 * 16384];  // 128 rows x 128B
    __shared__ __align__(16) unsigned char sB[2 * 8192];   //  64 rows x 128B

    const int tid  = threadIdx.x;
    const int wave = tid >> 6, lane = tid & 63;
    const int wm = wave >> 1, wn = wave & 1;
    const int q = lane >> 4, lr = lane & 15;

    // XCD-aware remap (R6-proven): each XCD owns a contiguous M-stripe.
    const int gx = gridDim.x, gy = gridDim.y;
    const int flat = blockIdx.y * gx + blockIdx.x;
    const int stripe = gy >> 3;
    const int xcd = flat & 7, local = flat >> 3;
    const int mt = xcd * stripe + (local % stripe);
    const int nt = local / stripe;
    const int m0 = mt * 128, n0 = nt * 64;

    floatx4 acc[4][2];
#pragma unroll
    for (int i = 0; i < 4; ++i)
#pragma unroll
        for (int j = 0; j < 2; ++j) acc[i][j] = (floatx4){0.f, 0.f, 0.f, 0.f};

    // staging: A 16KB = 16 x 1KB (4 instr/wave), B 8KB (2 instr/wave);
    // LDS slot s of row r holds global chunk s^(r&7) (16B chunks).
    const unsigned char* pa[4];
    const unsigned char* pb[2];
#pragma unroll
    for (int i = 0; i < 4; ++i) {
        const int idx = i * 256 + tid, row = idx >> 3, s = idx & 7;
        pa[i] = A + (size_t)(m0 + row) * K + ((s ^ (row & 7)) * 16);
    }
#pragma unroll
    for (int i = 0; i < 2; ++i) {
        const int idx = i * 256 + tid, row = idx >> 3, s = idx & 7;
        pb[i] = Bw + (size_t)(n0 + row) * K + ((s ^ (row & 7)) * 16);
    }

    // fragment LDS byte offsets (A frag i at +i*2048, B frag j at +j*2048;
    // (r+16i)&7 == r&7 so swizzle field is frag-invariant)
    const int rA = wm * 64 + lr, rB = wn * 32 + lr;
    const int oA0 = rA * 128 + (((2 * q)     ^ (rA & 7)) * 16);
    const int oA1 = rA * 128 + (((2 * q + 1) ^ (rA & 7)) * 16);
    const int oB0 = rB * 128 + (((2 * q)     ^ (rB & 7)) * 16);
    const int oB1 = rB * 128 + (((2 * q + 1) ^ (rB & 7)) * 16);

#define F8_ISSUE(ST) do {                                                      \
        _Pragma("unroll")                                                      \
        for (int i = 0; i < 4; ++i) {                                          \
            async_ld16(pa[i], &sA[(ST) * 16384 + (i * 256 + wave * 64) * 16]); \
            pa[i] += 128;                                                      \
        }                                                                      \
        _Pragma("unroll")                                                      \
        for (int i = 0; i < 2; ++i) {                                          \
            async_ld16(pb[i], &sB[(ST) * 8192 + (i * 256 + wave * 64) * 16]);  \
            pb[i] += 128;                                                      \
        }                                                                      \
    } while (0)

#define F8_STEP(ST) do {                                                       \
        asm volatile("" ::: "memory");                                         \
        __builtin_amdgcn_s_waitcnt(WAIT_VM(6));   /* this tile landed */       \
        __builtin_amdgcn_s_barrier();                                          \
        asm volatile("" ::: "memory");                                         \
        int8v a8[4], b8[2];                                                    \
        _Pragma("unroll")                                                      \
        for (int i = 0; i < 4; ++i) {                                          \
            int4v lo = *(const int4v*)&sA[(ST) * 16384 + oA0 + i * 2048];      \
            int4v hi = *(const int4v*)&sA[(ST) * 16384 + oA1 + i * 2048];      \
            a8[i] = __builtin_shufflevector(lo, hi, 0, 1, 2, 3, 4, 5, 6, 7);   \
        }                                                                      \
        _Pragma("unroll")                                                      \
        for (int j = 0; j < 2; ++j) {                                          \
            int4v lo = *(const int4v*)&sB[(ST) * 8192 + oB0 + j * 2048];       \
            int4v hi = *(const int4v*)&sB[(ST) * 8192 + oB1 + j * 2048];       \
            b8[j] = __builtin_shufflevector(lo, hi, 0, 1, 2, 3, 4, 5, 6, 7);   \
        }                                                                      \
        asm volatile("" ::: "memory");                                         \
        __builtin_amdgcn_s_waitcnt(WAIT_LGKM(0)); /* frags landed */           \
        __builtin_amdgcn_s_barrier();             /* stage reusable */         \
        asm volatile("" ::: "memory");                                         \
        F8_ISSUE(ST);                             /* tile kt+2 -> stage ST */  \
        _Pragma("unroll")                                                      \
        for (int i = 0; i < 4; ++i)                                            \
            _Pragma("unroll")                                                  \
            for (int j = 0; j < 2; ++j)                                        \
                acc[i][j] = __builtin_amdgcn_mfma_scale_f32_16x16x128_f8f6f4(  \
                    a8[i], b8[j], acc[i][j], 0, 0, 0, SA, 0, SB);              \
    } while (0)

    const int nit = K >> 8;        // (K/128)/2 double-steps; K mult of 256
    F8_ISSUE(0);
    F8_ISSUE(1);
    for (int it = 0; it < nit; ++it) {
        F8_STEP(0);
        F8_STEP(1);
    }
#undef F8_STEP
#undef F8_ISSUE
    asm volatile("" ::: "memory");
    __builtin_amdgcn_s_waitcnt(WAIT_VM(0));       // drain 2 garbage tail tiles

    // epilogue: C/D layout col = lane&15, row = (lane>>4)*4 + reg
    if (MODE == 0) {
#pragma unroll
        for (int i = 0; i < 4; ++i) {
            const int row = m0 + wm * 64 + i * 16 + q * 4;
#pragma unroll
            for (int j = 0; j < 2; ++j) {
                const int col = n0 + wn * 32 + j * 16 + lr;
                const float bc = bias[col];
#pragma unroll
                for (int r = 0; r < 4; ++r)
                    outb[(size_t)(row + r) * N + col] = __float2bfloat16(acc[i][j][r] + bc);
            }
        }
    } else if (MODE == 1) {
#pragma unroll
        for (int i = 0; i < 4; ++i) {
            float rs[4] = {0.f, 0.f, 0.f, 0.f};
#pragma unroll
            for (int j = 0; j < 2; ++j) {
                const int col = n0 + wn * 32 + j * 16 + lr;
                const float bc = bias[col];
#pragma unroll
                for (int r = 0; r < 4; ++r) {
                    float v = acc[i][j][r] + bc;
                    float sp = (v > 20.f) ? v : log1pf(expf(v));
                    rs[r] += sp;
                }
            }
#pragma unroll
            for (int r = 0; r < 4; ++r) {
                float v = rs[r];
                v += __shfl_xor(v, 1); v += __shfl_xor(v, 2);
                v += __shfl_xor(v, 4); v += __shfl_xor(v, 8);
                if (lr == 0)
                    atomicAdd(&rowsum[m0 + wm * 64 + i * 16 + q * 4 + r], v);
            }
        }
    } else {
        // out = resid + ys[row]*acc + bias  (y@W^T == diag(ys)*(S@W^T))
#pragma unroll
        for (int i = 0; i < 4; ++i) {
            const int row = m0 + wm * 64 + i * 16 + q * 4;
#pragma unroll
            for (int j = 0; j < 2; ++j) {
                const int col = n0 + wn * 32 + j * 16 + lr;
                const float bc = bias[col];
#pragma unroll
                for (int r = 0; r < 4; ++r) {
                    const size_t idx = (size_t)(row + r) * N + col;
                    outf[idx] = resid[idx] + ysv[row + r] * acc[i][j][r] + bc;
                }
            }
        }
    }
}

// ---------------------------------------------------------------------------
// fused elementwise pass over xp: depthwise conv(k=3)+bias+SiLU on main half
// -> xc (bf16, for bcd) + xc*16 (fp8, GEMM2 A); SiLU on gate half
// -> S*16 (fp8, GEMM3 A; ys factored out into GEMM3's epilogue).
// ---------------------------------------------------------------------------
__global__ void conv_gate_k(const __hip_bfloat16* __restrict__ xp,
                            const float* __restrict__ cw,
                            const float* __restrict__ cb,
                            __hip_bfloat16* __restrict__ xc,
                            int2* __restrict__ xc8,
                            int2* __restrict__ s8) {
    const int idx8 = blockIdx.x * blockDim.x + threadIdx.x;
    const int e = (idx8 & (Esz / 8 - 1)) * 8;
    const int r = idx8 >> 8;
    const int t = r & (Tsz - 1);
    const unsigned short* row0 = (const unsigned short*)(xp + (size_t)r * (2 * Esz) + e);
    short8 vm1 = (t > 0)       ? *(const short8*)(row0 - 2 * Esz) : (short8){0,0,0,0,0,0,0,0};
    short8 v00 = *(const short8*)row0;
    short8 vp1 = (t < Tsz - 1) ? *(const short8*)(row0 + 2 * Esz) : (short8){0,0,0,0,0,0,0,0};
    short8 o;
    float sil[8];
#pragma unroll
    for (int k = 0; k < 8; ++k) {
        const int ek = e + k;
        float v = bf2f((unsigned short)vm1[k]) * cw[ek * 3 + 0]
                + bf2f((unsigned short)v00[k]) * cw[ek * 3 + 1]
                + bf2f((unsigned short)vp1[k]) * cw[ek * 3 + 2] + cb[ek];
        sil[k] = v * sigmoidf_(v);
        __hip_bfloat16 h = __float2bfloat16(sil[k]);
        o[k] = *(short*)&h;
    }
    *(short8*)(xc + (size_t)idx8 * 8) = o;
    int2 p;
    p.x = pk_fp8x4(sil[0] * 16.f, sil[1] * 16.f, sil[2] * 16.f, sil[3] * 16.f);
    p.y = pk_fp8x4(sil[4] * 16.f, sil[5] * 16.f, sil[6] * 16.f, sil[7] * 16.f);
    xc8[idx8] = p;

    // gate half -> S = silu(gate) * 16, fp8
    short8 g = *(const short8*)(row0 + Esz);
    float sg[8];
#pragma unroll
    for (int k = 0; k < 8; ++k) {
        const float gv = bf2f((unsigned short)g[k]);
        sg[k] = gv * sigmoidf_(gv);
    }
    int2 ps;
    ps.x = pk_fp8x4(sg[0] * 16.f, sg[1] * 16.f, sg[2] * 16.f, sg[3] * 16.f);
    ps.y = pk_fp8x4(sg[4] * 16.f, sg[5] * 16.f, sg[6] * 16.f, sg[7] * 16.f);
    s8[idx8] = ps;
}

// ---------------------------------------------------------------------------
// pack B_w/C_w/D_w (each [16,2048] fp32) into Wb [48,2048] bf16
// ---------------------------------------------------------------------------
__global__ void pack_bcd(const float* __restrict__ Bw, const float* __restrict__ Cw,
                         const float* __restrict__ Dw, __hip_bfloat16* __restrict__ Wb) {
    const int idx = blockIdx.x * blockDim.x + threadIdx.x;
    if (idx >= 48 * Esz) return;
    const int row = idx >> 11, col = idx & (Esz - 1);
    float v;
    if (row < 16)      v = Bw[row * Esz + col];
    else if (row < 32) v = Cw[(row - 16) * Esz + col];
    else               v = Dw[(row - 32) * Esz + col];
    Wb[idx] = __float2bfloat16(v);
}

// ---------------------------------------------------------------------------
// B/C/D projections via MFMA skinny GEMM: xc[M,E] @ Wb[48,E]^T.
// ---------------------------------------------------------------------------
__launch_bounds__(256)
__global__ void bcd_mfma(const __hip_bfloat16* __restrict__ xc,
                         const __hip_bfloat16* __restrict__ Wb,
                         const float* __restrict__ Bb, const float* __restrict__ Cb,
                         const float* __restrict__ Db,
                         float* __restrict__ u, float* __restrict__ Ct) {
    __shared__ __align__(16) __hip_bfloat16 sA[64 * 32];
    __shared__ __align__(16) __hip_bfloat16 sW[48 * 32];
    const int tid = threadIdx.x;
    const int wave = tid >> 6, lane = tid & 63;
    const int q = lane >> 4, lr = lane & 15;
    const int m0 = blockIdx.x * 64;

    floatx4 acc[3];
#pragma unroll
    for (int j = 0; j < 3; ++j) acc[j] = (floatx4){0.f, 0.f, 0.f, 0.f};

    const int ra = wave * 16 + (lane >> 2);
    const int ca = (lane & 3) * 8;

    for (int kt = 0; kt < (Esz >> 5); ++kt) {
        const int k0 = kt << 5;
        __syncthreads();
        async_ld16(&xc[(size_t)(m0 + ra) * Esz + k0 + ca], &sA[wave * 512]);
        if (wave < 3)
            async_ld16(&Wb[(size_t)ra * Esz + k0 + ca], &sW[wave * 512]);
        __syncthreads();

        short8 af = *(const short8*)&sA[(wave * 16 + lr) * 32 + q * 8];
#pragma unroll
        for (int j = 0; j < 3; ++j) {
            short8 wf = *(const short8*)&sW[(j * 16 + lr) * 32 + q * 8];
            acc[j] = __builtin_amdgcn_mfma_f32_16x16x32_bf16(af, wf, acc[j], 0, 0, 0);
        }
    }

    const int row = m0 + wave * 16 + q * 4;
    const float bb = Bb[lr], cbv = Cb[lr], db = Db[lr];
#pragma unroll
    for (int r = 0; r < 4; ++r) {
        const float bt = acc[0][r] + bb;
        const float ct = acc[1][r] + cbv;
        const float dt = acc[2][r] + db;
        u [(size_t)(row + r) * Ssz + lr] = bt * dt;
        Ct[(size_t)(row + r) * Ssz + lr] = ct;
    }
}

// ---------------------------------------------------------------------------
// Sequential SSM scan (decay computed inline from rowsum).  One block/batch.
// ---------------------------------------------------------------------------
__global__ void scan_k(const float* __restrict__ rowsum, const float* __restrict__ u,
                       const float* __restrict__ Ct, float* __restrict__ ys) {
    const int b = blockIdx.x;
    const int tid = threadIdx.x;
    const int lane = tid & 63, wave = tid >> 6;
    __shared__ __align__(16) float su[256 * Ssz];
    __shared__ __align__(16) float sc[256 * Ssz];
    __shared__ float sp[256 * 17];
    __shared__ float sd[256];
    float st = 0.f;
    for (int t0 = 0; t0 < Tsz; t0 += 256) {
        __syncthreads();
        const float4* ub = (const float4*)(u  + ((size_t)b * Tsz + t0) * Ssz);
        const float4* cb = (const float4*)(Ct + ((size_t)b * Tsz + t0) * Ssz);
#pragma unroll
        for (int i = 0; i < 4; ++i) {
            ((float4*)su)[tid + i * 256] = ub[tid + i * 256];
            ((float4*)sc)[tid + i * 256] = cb[tid + i * 256];
        }
        {
            const float m = rowsum[b * Tsz + t0 + tid] * (1.f / (float)Esz);
            sd[tid] = expf(fminf(fmaxf(-m, -10.f), 10.f));
        }
        __syncthreads();
        if (wave == 0 && lane < 16) {
#pragma unroll 8
            for (int i = 0; i < 256; ++i) {
                st = st * sd[i] + su[i * Ssz + lane];
                sp[i * 17 + lane] = sc[i * Ssz + lane] * st;
            }
        }
        __syncthreads();
        float s = 0.f;
#pragma unroll
        for (int j = 0; j < 16; ++j) s += sp[tid * 17 + j];
        ys[b * Tsz + t0 + tid] = s;
    }
}

// ---------------------------------------------------------------------------
extern "C" void kernel_launch(void* const* d_in, const int* in_sizes, int n_in,
                              void* d_out, int out_size, void* d_ws, size_t ws_size,
                              hipStream_t stream) {
    const float* x      = (const float*)d_in[0];
    const float* in_w   = (const float*)d_in[1];
    const float* in_b   = (const float*)d_in[2];
    const float* conv_w = (const float*)d_in[3];
    const float* conv_b = (const float*)d_in[4];
    const float* dt_w   = (const float*)d_in[5];
    const float* dt_b   = (const float*)d_in[6];
    const float* B_w    = (const float*)d_in[7];
    const float* B_b    = (const float*)d_in[8];
    const float* C_w    = (const float*)d_in[9];
    const float* C_b    = (const float*)d_in[10];
    const float* D_w    = (const float*)d_in[11];
    const float* D_b    = (const float*)d_in[12];
    const float* out_w  = (const float*)d_in[13];
    const float* out_b  = (const float*)d_in[14];
    float* out = (float*)d_out;

    char* ws = (char*)d_ws;
    auto alloc = [&](size_t bytes) {
        char* p = ws;
        ws += (bytes + 255) & ~(size_t)255;
        return p;
    };
    unsigned char* x_f8    = (unsigned char*)alloc((size_t)Mrows * Dsz);          //  8 MB
    unsigned char* inw_f8  = (unsigned char*)alloc((size_t)2 * Esz * Dsz);        //  4 MB
    unsigned char* dtw_f8  = (unsigned char*)alloc((size_t)Esz * Esz);            //  4 MB
    unsigned char* outw_f8 = (unsigned char*)alloc((size_t)Dsz * Esz);            //  2 MB
    __hip_bfloat16* xp_bf  = (__hip_bfloat16*)alloc((size_t)Mrows * 2 * Esz * 2); // 64 MB
    __hip_bfloat16* xc_bf  = (__hip_bfloat16*)alloc((size_t)Mrows * Esz * 2);     // 32 MB
    unsigned char* xc_f8   = (unsigned char*)alloc((size_t)Mrows * Esz);          // 16 MB
    unsigned char* s_f8    = (unsigned char*)alloc((size_t)Mrows * Esz);          // 16 MB
    __hip_bfloat16* wb_bf  = (__hip_bfloat16*)alloc((size_t)48 * Esz * 2);
    float* rowsum = (float*)alloc(Mrows * 4);
    float* u_buf  = (float*)alloc((size_t)Mrows * Ssz * 4);
    float* ct_buf = (float*)alloc((size_t)Mrows * Ssz * 4);
    float* ys_buf = (float*)alloc(Mrows * 4);
    (void)alloc(65536);            // pad: fp8 tail over-reads stay inside ws

    hipMemsetAsync(rowsum, 0, Mrows * 4, stream);

    // conversions: x/in_w/dt_w/out_w -> fp8 (weights x64)
    cvt_all<<<4608, 256, 0, stream>>>((const float4*)x, (const float4*)in_w,
                                      (const float4*)dt_w, (const float4*)out_w,
                                      (int*)x_f8, (int*)inw_f8, (int*)dtw_f8,
                                      (int*)outw_f8);
    pack_bcd<<<48 * Esz / 256, 256, 0, stream>>>(B_w, C_w, D_w, wb_bf);

    // GEMM1 (MX-fp8 128x64): xp = x @ in_w^T + in_b  (8192x4096x1024) -> bf16
    // scales: A = x (2^0 -> 127), B = in_w*64 (2^-6 -> 121)
    gemm_f8<0, 127, 121><<<dim3(4096 / 64, Mrows / 128), 256, 0, stream>>>(
        x_f8, inw_f8, in_b, Mrows, 4096, 1024, xp_bf, nullptr, nullptr, nullptr, nullptr);

    // fused conv+SiLU (-> xc bf16, xc*16 fp8) + gate SiLU (-> S*16 fp8)
    conv_gate_k<<<(Mrows * Esz / 8) / 256, 256, 0, stream>>>(
        xp_bf, conv_w, conv_b, xc_bf, (int2*)xc_f8, (int2*)s_f8);

    // GEMM2 (MX-fp8): softplus(xc @ dt_w^T + dt_b) row-sums (8192x2048x2048)
    // scales: A = xc*16 (2^-4 -> 123), B = dt_w*64 (2^-6 -> 121)
    gemm_f8<1, 123, 121><<<dim3(Esz / 64, Mrows / 128), 256, 0, stream>>>(
        xc_f8, dtw_f8, dt_b, Mrows, Esz, Esz, nullptr, rowsum, nullptr, nullptr, nullptr);

    // B/C/D projections + u = Bt*Dt (bf16 xc)
    bcd_mfma<<<Mrows / 64, 256, 0, stream>>>(xc_bf, wb_bf, B_b, C_b, D_b, u_buf, ct_buf);

    // sequential scan (decay inline) -> ys
    scan_k<<<Bsz, 256, 0, stream>>>(rowsum, u_buf, ct_buf, ys_buf);

    // GEMM3 (MX-fp8): out = x + ys[row]*(S @ out_w^T) + out_b (8192x1024x2048)
    // scales: A = S*16 (2^-4 -> 123), B = out_w*64 (2^-6 -> 121)
    gemm_f8<2, 123, 121><<<dim3(Dsz / 64, Mrows / 128), 256, 0, stream>>>(
        s_f8, outw_f8, out_b, Mrows, Dsz, Esz, nullptr, nullptr, x, ys_buf, out);
}